// Round 10
// baseline (207.506 us; speedup 1.0000x reference)
//
#include <hip/hip_runtime.h>
#include <utility>

typedef unsigned int  u32;
typedef unsigned short u16;
typedef float f32x2 __attribute__((ext_vector_type(2)));

static __device__ __forceinline__ f32x2 fma2(f32x2 a, f32x2 b, f32x2 c){
  return __builtin_elementwise_fma(a, b, c);
}
static __device__ __forceinline__ f32x2 splat2(float v){ f32x2 r; r.x = v; r.y = v; return r; }

// ======================= compile-time real-CG generation =======================
// Mirrors the Python reference exactly: _cg, _u, _real_cg (einsum + R/I pick).

struct CEnt { int i, j, k; double c; };
struct PathTab { int n; int s; CEnt e[400]; };
struct cxd { double re, im; };
struct URow { int n; int col[2]; cxd v[2]; };
struct MTab { double M[9][9][9]; };

constexpr double FT[14] = {1.,1.,2.,6.,24.,120.,720.,5040.,40320.,362880.,
                           3628800.,39916800.,479001600.,6227020800.};

constexpr double cabs_(double x){ return x < 0 ? -x : x; }

constexpr double csqrt_(double x){
  if (x <= 0.) return 0.;
  double g = 1.;
  while (g*g < x) g *= 2.;
  for (int it = 0; it < 50; ++it) g = 0.5*(g + x/g);
  return g;
}

constexpr double cg_(int j1,int m1,int j2,int m2,int j3,int m3){
  if (m1 + m2 != m3) return 0.;
  int dj = j1 - j2; if (dj < 0) dj = -dj;
  if (j3 < dj || j3 > j1 + j2) return 0.;
  double preA = (double)(2*j3+1)*FT[j3+j1-j2]*FT[j3-j1+j2]*FT[j1+j2-j3]/FT[j1+j2+j3+1];
  double preB = FT[j3+m3]*FT[j3-m3]*FT[j1-m1]*FT[j1+m1]*FT[j2-m2]*FT[j2+m2];
  double pre = csqrt_(preA)*csqrt_(preB);
  int kmin = 0;
  if (j2-j3-m1 > kmin) kmin = j2-j3-m1;
  if (j1-j3+m2 > kmin) kmin = j1-j3+m2;
  int kmax = j1+j2-j3;
  if (j1-m1 < kmax) kmax = j1-m1;
  if (j2+m2 < kmax) kmax = j2+m2;
  double s = 0.;
  for (int k = kmin; k <= kmax; ++k){
    double d = FT[k]*FT[j1+j2-j3-k]*FT[j1-m1-k]*FT[j2+m2-k]*FT[j3-j2+m1+k]*FT[j3-j1-m2+k];
    s += ((k & 1) ? -1.0 : 1.0)/d;
  }
  return pre*s;
}

constexpr URow urow_(int l, int r){
  URow R{};
  const double s2 = 0.7071067811865476;
  int m = r - l;
  if (m == 0){ R.n = 1; R.col[0] = l; R.v[0] = {1., 0.}; }
  else if (m > 0){
    R.n = 2;
    R.col[0] = l + m; R.v[0] = { (m & 1) ? -s2 : s2, 0. };
    R.col[1] = l - m; R.v[1] = { s2, 0. };
  } else {
    int mm = -m;
    R.n = 2;
    R.col[0] = l - mm; R.v[0] = { 0., s2 };
    R.col[1] = l + mm; R.v[1] = { 0., (mm & 1) ? s2 : -s2 };
  }
  return R;
}

constexpr cxd cmul_(cxd a, cxd b){ return { a.re*b.re - a.im*b.im, a.re*b.im + a.im*b.re }; }

constexpr MTab buildM(int l1, int l2, int l3){
  const int n1 = 2*l1+1, n2 = 2*l2+1, n3 = 2*l3+1;
  double cgd[9][9][9] = {};
  for (int a = 0; a < n1; ++a)
    for (int b = 0; b < n2; ++b)
      for (int c = 0; c < n3; ++c)
        cgd[a][b][c] = cg_(l1, a-l1, l2, b-l2, l3, c-l3);

  double MR[9][9][9] = {}; double MI[9][9][9] = {};
  double sR = 0., sI = 0.;
  for (int i = 0; i < n1; ++i){
    URow u1 = urow_(l1, i);
    for (int j = 0; j < n2; ++j){
      URow u2 = urow_(l2, j);
      for (int k = 0; k < n3; ++k){
        URow u3 = urow_(l3, k);
        double mre = 0., mim = 0.;
        for (int a = 0; a < u1.n; ++a)
          for (int b = 0; b < u2.n; ++b)
            for (int c = 0; c < u3.n; ++c){
              double cv = cgd[u1.col[a]][u2.col[b]][u3.col[c]];
              if (cv != 0.){
                cxd t = cmul_(u1.v[a], u2.v[b]);
                cxd u3c = { u3.v[c].re, -u3.v[c].im };
                t = cmul_(t, u3c);
                mre += t.re*cv; mim += t.im*cv;
              }
            }
        MR[i][j][k] = mre; MI[i][j][k] = mim;
        sR += cabs_(mre); sI += cabs_(mim);
      }
    }
  }
  const bool useR = (sR >= sI);
  MTab out{};
  for (int i = 0; i < n1; ++i)
    for (int j = 0; j < n2; ++j)
      for (int k = 0; k < n3; ++k)
        out.M[i][j][k] = useR ? MR[i][j][k] : MI[i][j][k];
  return out;
}

// Diagonal family (l1==l2): merge (i,j)/(j,i), i<=j (exact; y1==y2).
constexpr PathTab buildDiag(int l, int l3){
  MTab A = buildM(l, l, l3);
  PathTab P{}; P.n = 0; P.s = 1;
  const int n = 2*l+1, n3 = 2*l3+1;
  for (int i = 0; i < n; ++i)
    for (int j = i; j < n; ++j)
      for (int k = 0; k < n3; ++k){
        double v = A.M[i][j][k];
        if (j > i) v += A.M[j][i][k];
        if (cabs_(v) > 1e-12){
          if (P.n >= 400) { P.n = -1; return P; }
          P.e[P.n].i = i; P.e[P.n].j = j; P.e[P.n].k = k; P.e[P.n].c = v; P.n++;
        }
      }
  return P;
}

// Off-diagonal pair (l1<l2): check C21[j,i,k] == s*C12[i,j,k], s=+-1.
constexpr PathTab buildPair(int l1, int l2, int l3){
  MTab A = buildM(l1, l2, l3);
  MTab B = buildM(l2, l1, l3);
  const int n1 = 2*l1+1, n2 = 2*l2+1, n3 = 2*l3+1;
  bool okp = true, okm = true;
  for (int i = 0; i < n1; ++i)
    for (int j = 0; j < n2; ++j)
      for (int k = 0; k < n3; ++k){
        double a = A.M[i][j][k], b = B.M[j][i][k];
        if (cabs_(b - a) > 1e-9) okp = false;
        if (cabs_(b + a) > 1e-9) okm = false;
      }
  PathTab P{}; P.n = 0; P.s = okp ? 1 : (okm ? -1 : 0);
  if (P.s == 0) return P;
  for (int i = 0; i < n1; ++i)
    for (int j = 0; j < n2; ++j)
      for (int k = 0; k < n3; ++k){
        double v = A.M[i][j][k];
        if (cabs_(v) > 1e-12){
          if (P.n >= 400) { P.n = -1; return P; }
          P.e[P.n].i = i; P.e[P.n].j = j; P.e[P.n].k = k; P.e[P.n].c = v; P.n++;
        }
      }
  return P;
}

// Raw single path (fallback for s==0 pairs).
constexpr PathTab buildSingleTab(int l1, int l2, int l3){
  MTab A = buildM(l1, l2, l3);
  const int n1 = 2*l1+1, n2 = 2*l2+1, n3 = 2*l3+1;
  PathTab P{}; P.n = 0; P.s = 1;
  for (int i = 0; i < n1; ++i)
    for (int j = 0; j < n2; ++j)
      for (int k = 0; k < n3; ++k){
        double v = A.M[i][j][k];
        if (cabs_(v) > 1e-12){
          if (P.n >= 400) { P.n = -1; return P; }
          P.e[P.n].i = i; P.e[P.n].j = j; P.e[P.n].k = k; P.e[P.n].c = v; P.n++;
        }
      }
  return P;
}

template<int L,int L3>          struct TD_ { static constexpr PathTab t = buildDiag(L, L3); };
template<int L1,int L2,int L3>  struct TP_ { static constexpr PathTab t = buildPair(L1, L2, L3); };
template<int L1,int L2,int L3>  struct TS_ { static constexpr PathTab t = buildSingleTab(L1, L2, L3); };

// weight index in the reference's path enumeration
constexpr int pidx(int lin, int lout, int a, int b, int c){
  int p = 0;
  for (int l1 = 0; l1 <= lin; ++l1)
    for (int l2 = 0; l2 <= lin; ++l2){
      int lo = l1 > l2 ? l1 - l2 : l2 - l1;
      int hi = (l1 + l2 < lout) ? l1 + l2 : lout;
      for (int l3 = lo; l3 <= hi; ++l3){
        if (l1 == a && l2 == b && l3 == c) return p;
        ++p;
      }
    }
  return -1;
}

// ======================= stage-1 group/slot layout =======================
#define G1LIST(X) \
  X(0, 0,0,0) X(1, 1,1,0) X(2, 1,1,1) X(3, 1,1,2) \
  X(4, 2,2,0) X(5, 2,2,1) X(6, 2,2,2) X(7, 2,2,3) X(8, 2,2,4) \
  X(9, 3,3,0) X(10,3,3,1) X(11,3,3,2) X(12,3,3,3) X(13,3,3,4) \
  X(14,0,1,1) X(15,0,2,2) X(16,0,3,3) \
  X(17,1,2,1) X(18,1,2,2) X(19,1,2,3) \
  X(20,1,3,2) X(21,1,3,3) X(22,1,3,4) \
  X(23,2,3,1) X(24,2,3,2) X(25,2,3,3) X(26,2,3,4)

struct Grp { int l1, l2, l3; };
#define G1ITEM(i,a,b,c) {a,b,c},
constexpr Grp G1A[27] = { G1LIST(G1ITEM) };
#undef G1ITEM

struct SlotTab { int base[28]; int s[27]; int total; };
constexpr SlotTab buildSlots(){
  SlotTab T{}; int b = 0;
  for (int i = 0; i < 27; ++i){
    int l1 = G1A[i].l1, l2 = G1A[i].l2, l3 = G1A[i].l3;
    int s = (l1 == l2) ? 1 : buildPair(l1, l2, l3).s;
    T.s[i] = s;
    T.base[i] = b;
    int w = 2*l3 + 1;
    b += (l1 != l2 && s == 0) ? 2*w : w;
  }
  T.base[27] = b; T.total = b;
  return T;
}
constexpr SlotTab ST1 = buildSlots();
constexpr int NS1v = ST1.total;   // 135 when all pairs satisfy s=+-1

// ======================= unrolled helpers =======================

// Kernel A (scalar, per-edge): o[BASE + k] += c * (y_i*y_j)
template<class TT,int L1,int L2,int BASE,int... S>
__device__ __forceinline__ void accS_(const float* __restrict__ y,
                                      float* __restrict__ o,
                                      std::integer_sequence<int, S...>){
  (( o[BASE + TT::t.e[S].k] +=
       (float)TT::t.e[S].c
       * (y[L1*L1 + TT::t.e[S].i] * y[L2*L2 + TT::t.e[S].j]) ), ...);
}
template<class TT,int L1,int L2,int BASE>
__device__ __forceinline__ void accS(const float* __restrict__ y,
                                     float* __restrict__ o){
  accS_<TT,L1,L2,BASE>(y, o, std::make_integer_sequence<int, TT::t.n>{});
}

// z-build (f-paired): z[L3^2+k] += w2 * splat(Se[BASE+k])
template<int L3,int BASE,int... K>
__device__ __forceinline__ void zadd2_(f32x2* __restrict__ z,
                                       const float* __restrict__ Se, f32x2 w,
                                       std::integer_sequence<int, K...>){
  (( z[L3*L3 + K] = fma2(w, splat2(Se[BASE + K]), z[L3*L3 + K]) ), ...);
}
template<int L3,int BASE>
__device__ __forceinline__ void zadd2(f32x2* __restrict__ z,
                                      const float* __restrict__ Se, f32x2 w){
  zadd2_<L3,BASE>(z, Se, w, std::make_integer_sequence<int, 2*L3+1>{});
}

// Stage 2, k-windowed (f-paired): o[kg-KLO] += c * (we * (zi*zj)) for kg in [KLO,KHI)
template<class TT,int L1,int L2,int L3,int KLO,int KHI,int S>
__device__ __forceinline__ void ap2k_one_(const f32x2* __restrict__ y,
                                          f32x2* __restrict__ o, f32x2 we){
  constexpr int kg = L3*L3 + TT::t.e[S].k;
  if constexpr (kg >= KLO && kg < KHI){
    o[kg - KLO] = fma2(splat2((float)TT::t.e[S].c),
                       we * (y[L1*L1 + TT::t.e[S].i] * y[L2*L2 + TT::t.e[S].j]),
                       o[kg - KLO]);
  }
}
template<class TT,int L1,int L2,int L3,int KLO,int KHI,int... S>
__device__ __forceinline__ void ap2k_(const f32x2* __restrict__ y,
                                      f32x2* __restrict__ o, f32x2 we,
                                      std::integer_sequence<int, S...>){
  ( ap2k_one_<TT,L1,L2,L3,KLO,KHI,S>(y, o, we), ... );
}
template<class TT,int L1,int L2,int L3,int KLO,int KHI>
__device__ __forceinline__ void apply_tabk_(const f32x2* __restrict__ y,
                                            f32x2* __restrict__ o, f32x2 we){
  ap2k_<TT,L1,L2,L3,KLO,KHI>(y, o, we,
      std::make_integer_sequence<int, TT::t.n>{});
}

// Stage-2 groups: 19 diag + 23 symmetric pairs (= 65 reference weights).
#define G2LIST(X) \
  X(0,0,0) X(1,1,0) X(1,1,1) X(1,1,2) \
  X(2,2,0) X(2,2,1) X(2,2,2) X(2,2,3) X(2,2,4) \
  X(3,3,0) X(3,3,1) X(3,3,2) X(3,3,3) X(3,3,4) \
  X(4,4,0) X(4,4,1) X(4,4,2) X(4,4,3) X(4,4,4) \
  X(0,1,1) X(0,2,2) X(0,3,3) X(0,4,4) \
  X(1,2,1) X(1,2,2) X(1,2,3) X(1,3,2) X(1,3,3) X(1,3,4) X(1,4,3) X(1,4,4) \
  X(2,3,1) X(2,3,2) X(2,3,3) X(2,3,4) X(2,4,2) X(2,4,3) X(2,4,4) \
  X(3,4,1) X(3,4,2) X(3,4,3) X(3,4,4)

// z-build device function (full z2[25] from LDS S-slice)
static __device__ __forceinline__ void zbuild(f32x2* __restrict__ z2,
                                              const float* __restrict__ Se,
                                              const float* __restrict__ w1s,
                                              int fp){
#define GB(gi,a,b,c) { \
    if constexpr (a == b) { \
      constexpr int pA_ = pidx(3,4,a,a,c); \
      f32x2 we = *(const f32x2*)&w1s[pA_*16 + 2*fp]; \
      zadd2<c, ST1.base[gi]>(z2, Se, we); \
    } else if constexpr (ST1.s[gi] != 0) { \
      constexpr int pA_ = pidx(3,4,a,b,c), pB_ = pidx(3,4,b,a,c); \
      f32x2 wA = *(const f32x2*)&w1s[pA_*16 + 2*fp]; \
      f32x2 wB = *(const f32x2*)&w1s[pB_*16 + 2*fp]; \
      f32x2 we; \
      if constexpr (ST1.s[gi] == 1) we = wA + wB; else we = wA - wB; \
      zadd2<c, ST1.base[gi]>(z2, Se, we); \
    } else { \
      constexpr int pA_ = pidx(3,4,a,b,c), pB_ = pidx(3,4,b,a,c); \
      f32x2 wA = *(const f32x2*)&w1s[pA_*16 + 2*fp]; \
      f32x2 wB = *(const f32x2*)&w1s[pB_*16 + 2*fp]; \
      zadd2<c, ST1.base[gi]>(z2, Se, wA); \
      zadd2<c, ST1.base[gi] + 2*c + 1>(z2, Se, wB); \
    } }
  G1LIST(GB)
#undef GB
}

// stage-2 device function over k-window [KLO,KHI)
template<int KLO,int KHI>
static __device__ __forceinline__ void stage2(const f32x2* __restrict__ z2,
                                              f32x2* __restrict__ o2,
                                              const float* __restrict__ w2s,
                                              int fp){
#define G2(a,b,c) { \
    if constexpr (a == b) { \
      constexpr int p_ = pidx(4,4,a,a,c); \
      f32x2 we = *(const f32x2*)&w2s[p_*16 + 2*fp]; \
      apply_tabk_<TD_<a,c>, a, b, c, KLO, KHI>(z2, o2, we); \
    } else if constexpr (TP_<a,b,c>::t.s != 0) { \
      constexpr int pA_ = pidx(4,4,a,b,c), pB_ = pidx(4,4,b,a,c); \
      f32x2 wA = *(const f32x2*)&w2s[pA_*16 + 2*fp]; \
      f32x2 wB = *(const f32x2*)&w2s[pB_*16 + 2*fp]; \
      f32x2 we; \
      if constexpr (TP_<a,b,c>::t.s == 1) we = wA + wB; else we = wA - wB; \
      apply_tabk_<TP_<a,b,c>, a, b, c, KLO, KHI>(z2, o2, we); \
    } else { \
      constexpr int pA_ = pidx(4,4,a,b,c), pB_ = pidx(4,4,b,a,c); \
      f32x2 wA = *(const f32x2*)&w2s[pA_*16 + 2*fp]; \
      f32x2 wB = *(const f32x2*)&w2s[pB_*16 + 2*fp]; \
      apply_tabk_<TS_<a,b,c>, a, b, c, KLO, KHI>(z2, o2, wA); \
      apply_tabk_<TS_<b,a,c>, b, a, c, KLO, KHI>(z2, o2, wB); \
    } }
  G2LIST(G2)
#undef G2
}

// ======================= kernel A: per-edge S basis =======================

__global__ __launch_bounds__(64) void acmd_kernelA(
    const float* __restrict__ disp,
    float* __restrict__ Sg, int E)
{
  __shared__ float tl[64 * NS1v];

  const int lt = threadIdx.x;
  const int e  = blockIdx.x*64 + lt;

  float Sout[NS1v];
#pragma unroll
  for (int k = 0; k < NS1v; ++k) Sout[k] = 0.f;

  if (e < E){
    const float dx = disp[3*e+0], dy = disp[3*e+1], dz = disp[3*e+2];
    const float r  = sqrtf(dx*dx + dy*dy + dz*dz);
    const float x  = r * (1.0f/5.0f);
    const float inv = 1.0f / fmaxf(r, 1e-9f);
    const float ux = dx*inv, uy = dy*inv, uz = dz*inv;
    const float cut = (x < 1.0f) ? expf(1.0f - 1.0f/(1.0f - x*x)) : 0.0f;

    const float sx2 = ux*ux, sy2 = uy*uy, sz2 = uz*uz;
    float s_[16];
    s_[0]  = 0.28209479177387814f;
    s_[1]  = 0.4886025119029199f*uy;
    s_[2]  = 0.4886025119029199f*uz;
    s_[3]  = 0.4886025119029199f*ux;
    s_[4]  = 1.0925484305920792f*ux*uy;
    s_[5]  = 1.0925484305920792f*uy*uz;
    s_[6]  = 0.31539156525252005f*(3.0f*sz2 - 1.0f);
    s_[7]  = 1.0925484305920792f*ux*uz;
    s_[8]  = 0.5462742152960396f*(sx2 - sy2);
    s_[9]  = 0.5900435899266435f*uy*(3.0f*sx2 - sy2);
    s_[10] = 2.890611442640554f*ux*uy*uz;
    s_[11] = 0.4570457994644658f*uy*(5.0f*sz2 - 1.0f);
    s_[12] = 0.3731763325901154f*uz*(5.0f*sz2 - 3.0f);
    s_[13] = 0.4570457994644658f*ux*(5.0f*sz2 - 1.0f);
    s_[14] = 1.445305721320277f*uz*(sx2 - sy2);
    s_[15] = 0.5900435899266435f*ux*(sx2 - 3.0f*sy2);
#pragma unroll
    for (int i = 0; i < 16; ++i) s_[i] *= cut;

#define GA(gi,a,b,c) { \
      if constexpr (a == b) accS<TD_<a,c>, a, b, ST1.base[gi]>(s_, Sout); \
      else if constexpr (ST1.s[gi] != 0) accS<TP_<a,b,c>, a, b, ST1.base[gi]>(s_, Sout); \
      else { accS<TS_<a,b,c>, a, b, ST1.base[gi]>(s_, Sout); \
             accS<TS_<b,a,c>, b, a, ST1.base[gi] + 2*c + 1>(s_, Sout); } }
    G1LIST(GA)
#undef GA
  }

#pragma unroll
  for (int k = 0; k < NS1v; ++k) tl[lt*NS1v + k] = Sout[k];
  __syncthreads();

  const long long base  = (long long)blockIdx.x * 64 * NS1v;
  const long long total = (long long)E * NS1v;
  for (int i = lt; i < 64*NS1v; i += 64){
    long long g = base + i;
    if (g < total) Sg[g] = tl[i];
  }
}

// ======================= kernel C: fused z-build + stage 2 =======================
// 256 threads = 2 k-halves x 16 edges x 8 f-pairs.
// R9 lesson: the z-build's 135 scalar in-loop LDS reads stalled issue (50% busy).
// Now h=0 computes z once (no duplication), shares raw z via LDS; both halves
// bulk-read it into registers -> stage2 runs pure-register (R6-B's 89%-busy mode).

#define KSPLIT 13
#define ZSTRIDE 52   // 25 f32x2 = 50 floats, padded to 52 for 16B alignment

__global__ __launch_bounds__(256, 2) void acmd_kernelC(
    const float* __restrict__ disp,
    const float* __restrict__ Sg,
    const float* __restrict__ w1g,
    const float* __restrict__ w2g,
    float* __restrict__ outf, int E)
{
  __shared__ float w1s[40*16];
  __shared__ float w2s[65*16];
  __shared__ float Ss[16 * NS1v];
  __shared__ __align__(16) float zsh[16*8*ZSTRIDE];   // 26.6 KB

  for (int i = threadIdx.x; i < 40*16; i += 256) w1s[i] = w1g[i];
  for (int i = threadIdx.x; i < 65*16; i += 256) w2s[i] = w2g[i];
  {
    const long long sbase = (long long)blockIdx.x * 16 * NS1v;
    const long long stot  = (long long)E * NS1v;
    for (int i = threadIdx.x; i < 16*NS1v; i += 256){
      long long g = sbase + i;
      Ss[i] = (g < stot) ? Sg[g] : 0.f;
    }
  }
  __syncthreads();

  const int h  = threadIdx.x >> 7;            // k-half 0/1 (wave-uniform)
  const int le = (threadIdx.x >> 3) & 15;     // local edge 0..15
  const int fp = threadIdx.x & 7;             // f-pair 0..7
  const int e  = blockIdx.x*16 + le;
  const bool act = (e < E);
  const int eg = act ? e : 0;

  float* zslot = &zsh[(le*8 + fp)*ZSTRIDE];

  f32x2 z2[25];
  if (h == 0){
#pragma unroll
    for (int k = 0; k < 25; ++k) z2[k] = splat2(0.f);
    const float* Se = &Ss[le * NS1v];
    zbuild(z2, Se, w1s, fp);
#pragma unroll
    for (int k = 0; k < 25; ++k) *(f32x2*)&zslot[2*k] = z2[k];
  }
  __syncthreads();
  if (h == 1){
#pragma unroll
    for (int k = 0; k < 25; ++k) z2[k] = *(const f32x2*)&zslot[2*k];
  }

  // rb^2 scaling (both halves, in registers)
  const float dx = disp[3*eg+0], dy = disp[3*eg+1], dz = disp[3*eg+2];
  const float r  = sqrtf(dx*dx + dy*dy + dz*dz);
  const float x  = r * (1.0f/5.0f);
  const float t0 = x * (float)(2*fp + 1);
  const float t1 = x * (float)(2*fp + 2);
  const float p0 = 3.14159265358979f * t0;
  const float p1 = 3.14159265358979f * t1;
  const float rb0 = (p0 > 1e-5f) ? (sinf(p0)/p0) : (1.0f - p0*p0*(1.0f/6.0f));
  const float rb1 = (p1 > 1e-5f) ? (sinf(p1)/p1) : (1.0f - p1*p1*(1.0f/6.0f));
  f32x2 rb2; rb2.x = rb0*rb0; rb2.y = rb1*rb1;
#pragma unroll
  for (int k = 0; k < 25; ++k) z2[k] = z2[k] * rb2;

  if (!act) return;   // all barriers are above; safe to exit

  // ---- stage 2 on this thread's k-window (pure-register) ----
  float* dst = outf + (long long)e * 400;
  if (h == 0){
    f32x2 o2[KSPLIT];
#pragma unroll
    for (int k = 0; k < KSPLIT; ++k) o2[k] = splat2(0.f);
    stage2<0, KSPLIT>(z2, o2, w2s, fp);
#pragma unroll
    for (int k = 0; k < KSPLIT; ++k)
      *(f32x2*)&dst[k*16 + 2*fp] = o2[k];
  } else {
    f32x2 o2[25 - KSPLIT];
#pragma unroll
    for (int k = 0; k < 25 - KSPLIT; ++k) o2[k] = splat2(0.f);
    stage2<KSPLIT, 25>(z2, o2, w2s, fp);
#pragma unroll
    for (int k = 0; k < 25 - KSPLIT; ++k)
      *(f32x2*)&dst[(KSPLIT + k)*16 + 2*fp] = o2[k];
  }
}

// ======================= launch =======================

extern "C" void kernel_launch(void* const* d_in, const int* in_sizes, int n_in,
                              void* d_out, int out_size, void* d_ws, size_t ws_size,
                              hipStream_t stream){
  const float* disp = (const float*)d_in[1];   // neighbour_displacements (E,3) f32
  const float* w1   = (const float*)d_in[3];   // tp_weights1 (40,16) f32
  const float* w2   = (const float*)d_in[4];   // tp_weights2 (65,16) f32
  const int E = in_sizes[1] / 3;

  const size_t needS = (size_t)E * NS1v * sizeof(float);
  if (ws_size < needS) return;                 // fail visibly if ws too small
  float* Sg = (float*)d_ws;

  const int blocksA = (E + 63) / 64;
  acmd_kernelA<<<blocksA, 64, 0, stream>>>(disp, Sg, E);

  const int blocksC = (E + 15) / 16;
  acmd_kernelC<<<blocksC, 256, 0, stream>>>(disp, Sg, w1, w2, (float*)d_out, E);
}

// Round 11
// 176.499 us; speedup vs baseline: 1.1757x; 1.1757x over previous
//
#include <hip/hip_runtime.h>
#include <utility>

typedef unsigned int  u32;
typedef unsigned short u16;
typedef float f32x2 __attribute__((ext_vector_type(2)));

static __device__ __forceinline__ f32x2 fma2(f32x2 a, f32x2 b, f32x2 c){
  return __builtin_elementwise_fma(a, b, c);
}
static __device__ __forceinline__ f32x2 splat2(float v){ f32x2 r; r.x = v; r.y = v; return r; }

// ======================= compile-time real-CG generation =======================
// Mirrors the Python reference exactly: _cg, _u, _real_cg (einsum + R/I pick).

struct CEnt { int i, j, k; double c; };
struct PathTab { int n; int s; CEnt e[400]; };
struct cxd { double re, im; };
struct URow { int n; int col[2]; cxd v[2]; };
struct MTab { double M[9][9][9]; };

constexpr double FT[14] = {1.,1.,2.,6.,24.,120.,720.,5040.,40320.,362880.,
                           3628800.,39916800.,479001600.,6227020800.};

constexpr double cabs_(double x){ return x < 0 ? -x : x; }

constexpr double csqrt_(double x){
  if (x <= 0.) return 0.;
  double g = 1.;
  while (g*g < x) g *= 2.;
  for (int it = 0; it < 50; ++it) g = 0.5*(g + x/g);
  return g;
}

constexpr double cg_(int j1,int m1,int j2,int m2,int j3,int m3){
  if (m1 + m2 != m3) return 0.;
  int dj = j1 - j2; if (dj < 0) dj = -dj;
  if (j3 < dj || j3 > j1 + j2) return 0.;
  double preA = (double)(2*j3+1)*FT[j3+j1-j2]*FT[j3-j1+j2]*FT[j1+j2-j3]/FT[j1+j2+j3+1];
  double preB = FT[j3+m3]*FT[j3-m3]*FT[j1-m1]*FT[j1+m1]*FT[j2-m2]*FT[j2+m2];
  double pre = csqrt_(preA)*csqrt_(preB);
  int kmin = 0;
  if (j2-j3-m1 > kmin) kmin = j2-j3-m1;
  if (j1-j3+m2 > kmin) kmin = j1-j3+m2;
  int kmax = j1+j2-j3;
  if (j1-m1 < kmax) kmax = j1-m1;
  if (j2+m2 < kmax) kmax = j2+m2;
  double s = 0.;
  for (int k = kmin; k <= kmax; ++k){
    double d = FT[k]*FT[j1+j2-j3-k]*FT[j1-m1-k]*FT[j2+m2-k]*FT[j3-j2+m1+k]*FT[j3-j1-m2+k];
    s += ((k & 1) ? -1.0 : 1.0)/d;
  }
  return pre*s;
}

constexpr URow urow_(int l, int r){
  URow R{};
  const double s2 = 0.7071067811865476;
  int m = r - l;
  if (m == 0){ R.n = 1; R.col[0] = l; R.v[0] = {1., 0.}; }
  else if (m > 0){
    R.n = 2;
    R.col[0] = l + m; R.v[0] = { (m & 1) ? -s2 : s2, 0. };
    R.col[1] = l - m; R.v[1] = { s2, 0. };
  } else {
    int mm = -m;
    R.n = 2;
    R.col[0] = l - mm; R.v[0] = { 0., s2 };
    R.col[1] = l + mm; R.v[1] = { 0., (mm & 1) ? s2 : -s2 };
  }
  return R;
}

constexpr cxd cmul_(cxd a, cxd b){ return { a.re*b.re - a.im*b.im, a.re*b.im + a.im*b.re }; }

constexpr MTab buildM(int l1, int l2, int l3){
  const int n1 = 2*l1+1, n2 = 2*l2+1, n3 = 2*l3+1;
  double cgd[9][9][9] = {};
  for (int a = 0; a < n1; ++a)
    for (int b = 0; b < n2; ++b)
      for (int c = 0; c < n3; ++c)
        cgd[a][b][c] = cg_(l1, a-l1, l2, b-l2, l3, c-l3);

  double MR[9][9][9] = {}; double MI[9][9][9] = {};
  double sR = 0., sI = 0.;
  for (int i = 0; i < n1; ++i){
    URow u1 = urow_(l1, i);
    for (int j = 0; j < n2; ++j){
      URow u2 = urow_(l2, j);
      for (int k = 0; k < n3; ++k){
        URow u3 = urow_(l3, k);
        double mre = 0., mim = 0.;
        for (int a = 0; a < u1.n; ++a)
          for (int b = 0; b < u2.n; ++b)
            for (int c = 0; c < u3.n; ++c){
              double cv = cgd[u1.col[a]][u2.col[b]][u3.col[c]];
              if (cv != 0.){
                cxd t = cmul_(u1.v[a], u2.v[b]);
                cxd u3c = { u3.v[c].re, -u3.v[c].im };
                t = cmul_(t, u3c);
                mre += t.re*cv; mim += t.im*cv;
              }
            }
        MR[i][j][k] = mre; MI[i][j][k] = mim;
        sR += cabs_(mre); sI += cabs_(mim);
      }
    }
  }
  const bool useR = (sR >= sI);
  MTab out{};
  for (int i = 0; i < n1; ++i)
    for (int j = 0; j < n2; ++j)
      for (int k = 0; k < n3; ++k)
        out.M[i][j][k] = useR ? MR[i][j][k] : MI[i][j][k];
  return out;
}

// Diagonal family (l1==l2): merge (i,j)/(j,i), i<=j (exact; y1==y2).
constexpr PathTab buildDiag(int l, int l3){
  MTab A = buildM(l, l, l3);
  PathTab P{}; P.n = 0; P.s = 1;
  const int n = 2*l+1, n3 = 2*l3+1;
  for (int i = 0; i < n; ++i)
    for (int j = i; j < n; ++j)
      for (int k = 0; k < n3; ++k){
        double v = A.M[i][j][k];
        if (j > i) v += A.M[j][i][k];
        if (cabs_(v) > 1e-12){
          if (P.n >= 400) { P.n = -1; return P; }
          P.e[P.n].i = i; P.e[P.n].j = j; P.e[P.n].k = k; P.e[P.n].c = v; P.n++;
        }
      }
  return P;
}

// Off-diagonal pair (l1<l2): check C21[j,i,k] == s*C12[i,j,k], s=+-1.
constexpr PathTab buildPair(int l1, int l2, int l3){
  MTab A = buildM(l1, l2, l3);
  MTab B = buildM(l2, l1, l3);
  const int n1 = 2*l1+1, n2 = 2*l2+1, n3 = 2*l3+1;
  bool okp = true, okm = true;
  for (int i = 0; i < n1; ++i)
    for (int j = 0; j < n2; ++j)
      for (int k = 0; k < n3; ++k){
        double a = A.M[i][j][k], b = B.M[j][i][k];
        if (cabs_(b - a) > 1e-9) okp = false;
        if (cabs_(b + a) > 1e-9) okm = false;
      }
  PathTab P{}; P.n = 0; P.s = okp ? 1 : (okm ? -1 : 0);
  if (P.s == 0) return P;
  for (int i = 0; i < n1; ++i)
    for (int j = 0; j < n2; ++j)
      for (int k = 0; k < n3; ++k){
        double v = A.M[i][j][k];
        if (cabs_(v) > 1e-12){
          if (P.n >= 400) { P.n = -1; return P; }
          P.e[P.n].i = i; P.e[P.n].j = j; P.e[P.n].k = k; P.e[P.n].c = v; P.n++;
        }
      }
  return P;
}

// Raw single path (fallback for s==0 pairs).
constexpr PathTab buildSingleTab(int l1, int l2, int l3){
  MTab A = buildM(l1, l2, l3);
  const int n1 = 2*l1+1, n2 = 2*l2+1, n3 = 2*l3+1;
  PathTab P{}; P.n = 0; P.s = 1;
  for (int i = 0; i < n1; ++i)
    for (int j = 0; j < n2; ++j)
      for (int k = 0; k < n3; ++k){
        double v = A.M[i][j][k];
        if (cabs_(v) > 1e-12){
          if (P.n >= 400) { P.n = -1; return P; }
          P.e[P.n].i = i; P.e[P.n].j = j; P.e[P.n].k = k; P.e[P.n].c = v; P.n++;
        }
      }
  return P;
}

template<int L,int L3>          struct TD_ { static constexpr PathTab t = buildDiag(L, L3); };
template<int L1,int L2,int L3>  struct TP_ { static constexpr PathTab t = buildPair(L1, L2, L3); };
template<int L1,int L2,int L3>  struct TS_ { static constexpr PathTab t = buildSingleTab(L1, L2, L3); };

// weight index in the reference's path enumeration
constexpr int pidx(int lin, int lout, int a, int b, int c){
  int p = 0;
  for (int l1 = 0; l1 <= lin; ++l1)
    for (int l2 = 0; l2 <= lin; ++l2){
      int lo = l1 > l2 ? l1 - l2 : l2 - l1;
      int hi = (l1 + l2 < lout) ? l1 + l2 : lout;
      for (int l3 = lo; l3 <= hi; ++l3){
        if (l1 == a && l2 == b && l3 == c) return p;
        ++p;
      }
    }
  return -1;
}

// ======================= stage-1 group/slot layout =======================
#define G1LIST(X) \
  X(0, 0,0,0) X(1, 1,1,0) X(2, 1,1,1) X(3, 1,1,2) \
  X(4, 2,2,0) X(5, 2,2,1) X(6, 2,2,2) X(7, 2,2,3) X(8, 2,2,4) \
  X(9, 3,3,0) X(10,3,3,1) X(11,3,3,2) X(12,3,3,3) X(13,3,3,4) \
  X(14,0,1,1) X(15,0,2,2) X(16,0,3,3) \
  X(17,1,2,1) X(18,1,2,2) X(19,1,2,3) \
  X(20,1,3,2) X(21,1,3,3) X(22,1,3,4) \
  X(23,2,3,1) X(24,2,3,2) X(25,2,3,3) X(26,2,3,4)

struct Grp { int l1, l2, l3; };
#define G1ITEM(i,a,b,c) {a,b,c},
constexpr Grp G1A[27] = { G1LIST(G1ITEM) };
#undef G1ITEM

struct SlotTab { int base[28]; int s[27]; int total; };
constexpr SlotTab buildSlots(){
  SlotTab T{}; int b = 0;
  for (int i = 0; i < 27; ++i){
    int l1 = G1A[i].l1, l2 = G1A[i].l2, l3 = G1A[i].l3;
    int s = (l1 == l2) ? 1 : buildPair(l1, l2, l3).s;
    T.s[i] = s;
    T.base[i] = b;
    int w = 2*l3 + 1;
    b += (l1 != l2 && s == 0) ? 2*w : w;
  }
  T.base[27] = b; T.total = b;
  return T;
}
constexpr SlotTab ST1 = buildSlots();
constexpr int NS1v = ST1.total;   // 135 when all pairs satisfy s=+-1

// ======================= unrolled helpers =======================

// Kernel A (scalar, per-edge): o[BASE + k] += c * (y_i*y_j)
template<class TT,int L1,int L2,int BASE,int... S>
__device__ __forceinline__ void accS_(const float* __restrict__ y,
                                      float* __restrict__ o,
                                      std::integer_sequence<int, S...>){
  (( o[BASE + TT::t.e[S].k] +=
       (float)TT::t.e[S].c
       * (y[L1*L1 + TT::t.e[S].i] * y[L2*L2 + TT::t.e[S].j]) ), ...);
}
template<class TT,int L1,int L2,int BASE>
__device__ __forceinline__ void accS(const float* __restrict__ y,
                                     float* __restrict__ o){
  accS_<TT,L1,L2,BASE>(y, o, std::make_integer_sequence<int, TT::t.n>{});
}

// z-build (f-paired): z[L3^2+k] += w2 * splat(Se[BASE+k])
template<int L3,int BASE,int... K>
__device__ __forceinline__ void zadd2_(f32x2* __restrict__ z,
                                       const float* __restrict__ Se, f32x2 w,
                                       std::integer_sequence<int, K...>){
  (( z[L3*L3 + K] = fma2(w, splat2(Se[BASE + K]), z[L3*L3 + K]) ), ...);
}
template<int L3,int BASE>
__device__ __forceinline__ void zadd2(f32x2* __restrict__ z,
                                      const float* __restrict__ Se, f32x2 w){
  zadd2_<L3,BASE>(z, Se, w, std::make_integer_sequence<int, 2*L3+1>{});
}

// Stage 2 (f-paired, full k): o[kg] += c * (we * (zi*zj))
template<class TT,int L1,int L2,int L3,int S>
__device__ __forceinline__ void ap2_one_(const f32x2* __restrict__ y,
                                         f32x2* __restrict__ o, f32x2 we){
  constexpr int kg = L3*L3 + TT::t.e[S].k;
  o[kg] = fma2(splat2((float)TT::t.e[S].c),
               we * (y[L1*L1 + TT::t.e[S].i] * y[L2*L2 + TT::t.e[S].j]),
               o[kg]);
}
template<class TT,int L1,int L2,int L3,int... S>
__device__ __forceinline__ void ap2_(const f32x2* __restrict__ y,
                                     f32x2* __restrict__ o, f32x2 we,
                                     std::integer_sequence<int, S...>){
  ( ap2_one_<TT,L1,L2,L3,S>(y, o, we), ... );
}
template<class TT,int L1,int L2,int L3>
__device__ __forceinline__ void apply_tab2_(const f32x2* __restrict__ y,
                                            f32x2* __restrict__ o, f32x2 we){
  ap2_<TT,L1,L2,L3>(y, o, we, std::make_integer_sequence<int, TT::t.n>{});
}

// Stage-2 groups: 19 diag + 23 symmetric pairs (= 65 reference weights).
#define G2LIST(X) \
  X(0,0,0) X(1,1,0) X(1,1,1) X(1,1,2) \
  X(2,2,0) X(2,2,1) X(2,2,2) X(2,2,3) X(2,2,4) \
  X(3,3,0) X(3,3,1) X(3,3,2) X(3,3,3) X(3,3,4) \
  X(4,4,0) X(4,4,1) X(4,4,2) X(4,4,3) X(4,4,4) \
  X(0,1,1) X(0,2,2) X(0,3,3) X(0,4,4) \
  X(1,2,1) X(1,2,2) X(1,2,3) X(1,3,2) X(1,3,3) X(1,3,4) X(1,4,3) X(1,4,4) \
  X(2,3,1) X(2,3,2) X(2,3,3) X(2,3,4) X(2,4,2) X(2,4,3) X(2,4,4) \
  X(3,4,1) X(3,4,2) X(3,4,3) X(3,4,4)

// z-build device function (full z2[25] from LDS S-slice)
static __device__ __forceinline__ void zbuild(f32x2* __restrict__ z2,
                                              const float* __restrict__ Se,
                                              const float* __restrict__ w1s,
                                              int fp){
#define GB(gi,a,b,c) { \
    if constexpr (a == b) { \
      constexpr int pA_ = pidx(3,4,a,a,c); \
      f32x2 we = *(const f32x2*)&w1s[pA_*16 + 2*fp]; \
      zadd2<c, ST1.base[gi]>(z2, Se, we); \
    } else if constexpr (ST1.s[gi] != 0) { \
      constexpr int pA_ = pidx(3,4,a,b,c), pB_ = pidx(3,4,b,a,c); \
      f32x2 wA = *(const f32x2*)&w1s[pA_*16 + 2*fp]; \
      f32x2 wB = *(const f32x2*)&w1s[pB_*16 + 2*fp]; \
      f32x2 we; \
      if constexpr (ST1.s[gi] == 1) we = wA + wB; else we = wA - wB; \
      zadd2<c, ST1.base[gi]>(z2, Se, we); \
    } else { \
      constexpr int pA_ = pidx(3,4,a,b,c), pB_ = pidx(3,4,b,a,c); \
      f32x2 wA = *(const f32x2*)&w1s[pA_*16 + 2*fp]; \
      f32x2 wB = *(const f32x2*)&w1s[pB_*16 + 2*fp]; \
      zadd2<c, ST1.base[gi]>(z2, Se, wA); \
      zadd2<c, ST1.base[gi] + 2*c + 1>(z2, Se, wB); \
    } }
  G1LIST(GB)
#undef GB
}

// stage-2 device function, full k range, pure-register
static __device__ __forceinline__ void stage2f(const f32x2* __restrict__ z2,
                                               f32x2* __restrict__ o2,
                                               const float* __restrict__ w2s,
                                               int fp){
#define G2(a,b,c) { \
    if constexpr (a == b) { \
      constexpr int p_ = pidx(4,4,a,a,c); \
      f32x2 we = *(const f32x2*)&w2s[p_*16 + 2*fp]; \
      apply_tab2_<TD_<a,c>, a, b, c>(z2, o2, we); \
    } else if constexpr (TP_<a,b,c>::t.s != 0) { \
      constexpr int pA_ = pidx(4,4,a,b,c), pB_ = pidx(4,4,b,a,c); \
      f32x2 wA = *(const f32x2*)&w2s[pA_*16 + 2*fp]; \
      f32x2 wB = *(const f32x2*)&w2s[pB_*16 + 2*fp]; \
      f32x2 we; \
      if constexpr (TP_<a,b,c>::t.s == 1) we = wA + wB; else we = wA - wB; \
      apply_tab2_<TP_<a,b,c>, a, b, c>(z2, o2, we); \
    } else { \
      constexpr int pA_ = pidx(4,4,a,b,c), pB_ = pidx(4,4,b,a,c); \
      f32x2 wA = *(const f32x2*)&w2s[pA_*16 + 2*fp]; \
      f32x2 wB = *(const f32x2*)&w2s[pB_*16 + 2*fp]; \
      apply_tab2_<TS_<a,b,c>, a, b, c>(z2, o2, wA); \
      apply_tab2_<TS_<b,a,c>, b, a, c>(z2, o2, wB); \
    } }
  G2LIST(G2)
#undef G2
}

// ======================= kernel A: per-edge S basis =======================

__global__ __launch_bounds__(64) void acmd_kernelA(
    const float* __restrict__ disp,
    float* __restrict__ Sg, int E)
{
  __shared__ float tl[64 * NS1v];

  const int lt = threadIdx.x;
  const int e  = blockIdx.x*64 + lt;

  float Sout[NS1v];
#pragma unroll
  for (int k = 0; k < NS1v; ++k) Sout[k] = 0.f;

  if (e < E){
    const float dx = disp[3*e+0], dy = disp[3*e+1], dz = disp[3*e+2];
    const float r  = sqrtf(dx*dx + dy*dy + dz*dz);
    const float x  = r * (1.0f/5.0f);
    const float inv = 1.0f / fmaxf(r, 1e-9f);
    const float ux = dx*inv, uy = dy*inv, uz = dz*inv;
    const float cut = (x < 1.0f) ? expf(1.0f - 1.0f/(1.0f - x*x)) : 0.0f;

    const float sx2 = ux*ux, sy2 = uy*uy, sz2 = uz*uz;
    float s_[16];
    s_[0]  = 0.28209479177387814f;
    s_[1]  = 0.4886025119029199f*uy;
    s_[2]  = 0.4886025119029199f*uz;
    s_[3]  = 0.4886025119029199f*ux;
    s_[4]  = 1.0925484305920792f*ux*uy;
    s_[5]  = 1.0925484305920792f*uy*uz;
    s_[6]  = 0.31539156525252005f*(3.0f*sz2 - 1.0f);
    s_[7]  = 1.0925484305920792f*ux*uz;
    s_[8]  = 0.5462742152960396f*(sx2 - sy2);
    s_[9]  = 0.5900435899266435f*uy*(3.0f*sx2 - sy2);
    s_[10] = 2.890611442640554f*ux*uy*uz;
    s_[11] = 0.4570457994644658f*uy*(5.0f*sz2 - 1.0f);
    s_[12] = 0.3731763325901154f*uz*(5.0f*sz2 - 3.0f);
    s_[13] = 0.4570457994644658f*ux*(5.0f*sz2 - 1.0f);
    s_[14] = 1.445305721320277f*uz*(sx2 - sy2);
    s_[15] = 0.5900435899266435f*ux*(sx2 - 3.0f*sy2);
#pragma unroll
    for (int i = 0; i < 16; ++i) s_[i] *= cut;

#define GA(gi,a,b,c) { \
      if constexpr (a == b) accS<TD_<a,c>, a, b, ST1.base[gi]>(s_, Sout); \
      else if constexpr (ST1.s[gi] != 0) accS<TP_<a,b,c>, a, b, ST1.base[gi]>(s_, Sout); \
      else { accS<TS_<a,b,c>, a, b, ST1.base[gi]>(s_, Sout); \
             accS<TS_<b,a,c>, b, a, ST1.base[gi] + 2*c + 1>(s_, Sout); } }
    G1LIST(GA)
#undef GA
  }

#pragma unroll
  for (int k = 0; k < NS1v; ++k) tl[lt*NS1v + k] = Sout[k];
  __syncthreads();

  const long long base  = (long long)blockIdx.x * 64 * NS1v;
  const long long total = (long long)E * NS1v;
  for (int i = lt; i < 64*NS1v; i += 64){
    long long g = base + i;
    if (g < total) Sg[g] = tl[i];
  }
}

// ======================= kernel C: fused z-build + stage 2, full-k =============
// 256 threads = 32 edges x 8 f-pairs. One thread owns all 25 output k's:
// no duplicated z-build, no duplicated products (R10 lesson: pk ops are
// FLOP-rate-neutral; instruction COUNT is the limit).

__global__ __launch_bounds__(256, 2) void acmd_kernelC(
    const float* __restrict__ disp,
    const float* __restrict__ Sg,
    const float* __restrict__ w1g,
    const float* __restrict__ w2g,
    float* __restrict__ outf, int E)
{
  __shared__ float w1s[40*16];
  __shared__ float w2s[65*16];
  __shared__ float Ss[32 * NS1v];

  for (int i = threadIdx.x; i < 40*16; i += 256) w1s[i] = w1g[i];
  for (int i = threadIdx.x; i < 65*16; i += 256) w2s[i] = w2g[i];
  {
    const long long sbase = (long long)blockIdx.x * 32 * NS1v;
    const long long stot  = (long long)E * NS1v;
    for (int i = threadIdx.x; i < 32*NS1v; i += 256){
      long long g = sbase + i;
      Ss[i] = (g < stot) ? Sg[g] : 0.f;
    }
  }
  __syncthreads();

  const int le = threadIdx.x >> 3;            // local edge 0..31
  const int fp = threadIdx.x & 7;             // f-pair 0..7
  const int e  = blockIdx.x*32 + le;
  if (e >= E) return;                         // no barriers below

  // ---- z-build (registers) ----
  const float dx = disp[3*e+0], dy = disp[3*e+1], dz = disp[3*e+2];
  const float r  = sqrtf(dx*dx + dy*dy + dz*dz);
  const float x  = r * (1.0f/5.0f);
  const float t0 = x * (float)(2*fp + 1);
  const float t1 = x * (float)(2*fp + 2);
  const float p0 = 3.14159265358979f * t0;
  const float p1 = 3.14159265358979f * t1;
  const float rb0 = (p0 > 1e-5f) ? (sinf(p0)/p0) : (1.0f - p0*p0*(1.0f/6.0f));
  const float rb1 = (p1 > 1e-5f) ? (sinf(p1)/p1) : (1.0f - p1*p1*(1.0f/6.0f));
  f32x2 rb2; rb2.x = rb0*rb0; rb2.y = rb1*rb1;

  const float* Se = &Ss[le * NS1v];

  f32x2 z2[25];
#pragma unroll
  for (int k = 0; k < 25; ++k) z2[k] = splat2(0.f);
  zbuild(z2, Se, w1s, fp);
#pragma unroll
  for (int k = 0; k < 25; ++k) z2[k] = z2[k] * rb2;

  // ---- stage 2 (full k, pure-register) ----
  f32x2 o2[25];
#pragma unroll
  for (int k = 0; k < 25; ++k) o2[k] = splat2(0.f);
  stage2f(z2, o2, w2s, fp);

  float* dst = outf + (long long)e * 400;
#pragma unroll
  for (int k = 0; k < 25; ++k)
    *(f32x2*)&dst[k*16 + 2*fp] = o2[k];
}

// ======================= launch =======================

extern "C" void kernel_launch(void* const* d_in, const int* in_sizes, int n_in,
                              void* d_out, int out_size, void* d_ws, size_t ws_size,
                              hipStream_t stream){
  const float* disp = (const float*)d_in[1];   // neighbour_displacements (E,3) f32
  const float* w1   = (const float*)d_in[3];   // tp_weights1 (40,16) f32
  const float* w2   = (const float*)d_in[4];   // tp_weights2 (65,16) f32
  const int E = in_sizes[1] / 3;

  const size_t needS = (size_t)E * NS1v * sizeof(float);
  if (ws_size < needS) return;                 // fail visibly if ws too small
  float* Sg = (float*)d_ws;

  const int blocksA = (E + 63) / 64;
  acmd_kernelA<<<blocksA, 64, 0, stream>>>(disp, Sg, E);

  const int blocksC = (E + 31) / 32;
  acmd_kernelC<<<blocksC, 256, 0, stream>>>(disp, Sg, w1, w2, (float*)d_out, E);
}

// Round 12
// 146.632 us; speedup vs baseline: 1.4152x; 1.2037x over previous
//
#include <hip/hip_runtime.h>
#include <utility>

typedef unsigned int  u32;
typedef unsigned short u16;

// ======================= compile-time real-CG generation =======================
// Mirrors the Python reference exactly: _cg, _u, _real_cg (einsum + R/I pick).

struct CEnt { int i, j, k; double c; };
struct PathTab { int n; int s; CEnt e[400]; };
struct cxd { double re, im; };
struct URow { int n; int col[2]; cxd v[2]; };
struct MTab { double M[9][9][9]; };

constexpr double FT[14] = {1.,1.,2.,6.,24.,120.,720.,5040.,40320.,362880.,
                           3628800.,39916800.,479001600.,6227020800.};

constexpr double cabs_(double x){ return x < 0 ? -x : x; }

constexpr double csqrt_(double x){
  if (x <= 0.) return 0.;
  double g = 1.;
  while (g*g < x) g *= 2.;
  for (int it = 0; it < 50; ++it) g = 0.5*(g + x/g);
  return g;
}

constexpr double cg_(int j1,int m1,int j2,int m2,int j3,int m3){
  if (m1 + m2 != m3) return 0.;
  int dj = j1 - j2; if (dj < 0) dj = -dj;
  if (j3 < dj || j3 > j1 + j2) return 0.;
  double preA = (double)(2*j3+1)*FT[j3+j1-j2]*FT[j3-j1+j2]*FT[j1+j2-j3]/FT[j1+j2+j3+1];
  double preB = FT[j3+m3]*FT[j3-m3]*FT[j1-m1]*FT[j1+m1]*FT[j2-m2]*FT[j2+m2];
  double pre = csqrt_(preA)*csqrt_(preB);
  int kmin = 0;
  if (j2-j3-m1 > kmin) kmin = j2-j3-m1;
  if (j1-j3+m2 > kmin) kmin = j1-j3+m2;
  int kmax = j1+j2-j3;
  if (j1-m1 < kmax) kmax = j1-m1;
  if (j2+m2 < kmax) kmax = j2+m2;
  double s = 0.;
  for (int k = kmin; k <= kmax; ++k){
    double d = FT[k]*FT[j1+j2-j3-k]*FT[j1-m1-k]*FT[j2+m2-k]*FT[j3-j2+m1+k]*FT[j3-j1-m2+k];
    s += ((k & 1) ? -1.0 : 1.0)/d;
  }
  return pre*s;
}

constexpr URow urow_(int l, int r){
  URow R{};
  const double s2 = 0.7071067811865476;
  int m = r - l;
  if (m == 0){ R.n = 1; R.col[0] = l; R.v[0] = {1., 0.}; }
  else if (m > 0){
    R.n = 2;
    R.col[0] = l + m; R.v[0] = { (m & 1) ? -s2 : s2, 0. };
    R.col[1] = l - m; R.v[1] = { s2, 0. };
  } else {
    int mm = -m;
    R.n = 2;
    R.col[0] = l - mm; R.v[0] = { 0., s2 };
    R.col[1] = l + mm; R.v[1] = { 0., (mm & 1) ? s2 : -s2 };
  }
  return R;
}

constexpr cxd cmul_(cxd a, cxd b){ return { a.re*b.re - a.im*b.im, a.re*b.im + a.im*b.re }; }

constexpr MTab buildM(int l1, int l2, int l3){
  const int n1 = 2*l1+1, n2 = 2*l2+1, n3 = 2*l3+1;
  double cgd[9][9][9] = {};
  for (int a = 0; a < n1; ++a)
    for (int b = 0; b < n2; ++b)
      for (int c = 0; c < n3; ++c)
        cgd[a][b][c] = cg_(l1, a-l1, l2, b-l2, l3, c-l3);

  double MR[9][9][9] = {}; double MI[9][9][9] = {};
  double sR = 0., sI = 0.;
  for (int i = 0; i < n1; ++i){
    URow u1 = urow_(l1, i);
    for (int j = 0; j < n2; ++j){
      URow u2 = urow_(l2, j);
      for (int k = 0; k < n3; ++k){
        URow u3 = urow_(l3, k);
        double mre = 0., mim = 0.;
        for (int a = 0; a < u1.n; ++a)
          for (int b = 0; b < u2.n; ++b)
            for (int c = 0; c < u3.n; ++c){
              double cv = cgd[u1.col[a]][u2.col[b]][u3.col[c]];
              if (cv != 0.){
                cxd t = cmul_(u1.v[a], u2.v[b]);
                cxd u3c = { u3.v[c].re, -u3.v[c].im };
                t = cmul_(t, u3c);
                mre += t.re*cv; mim += t.im*cv;
              }
            }
        MR[i][j][k] = mre; MI[i][j][k] = mim;
        sR += cabs_(mre); sI += cabs_(mim);
      }
    }
  }
  const bool useR = (sR >= sI);
  MTab out{};
  for (int i = 0; i < n1; ++i)
    for (int j = 0; j < n2; ++j)
      for (int k = 0; k < n3; ++k)
        out.M[i][j][k] = useR ? MR[i][j][k] : MI[i][j][k];
  return out;
}

// Diagonal family (l1==l2): merge (i,j)/(j,i), i<=j (exact; y1==y2).
constexpr PathTab buildDiag(int l, int l3){
  MTab A = buildM(l, l, l3);
  PathTab P{}; P.n = 0; P.s = 1;
  const int n = 2*l+1, n3 = 2*l3+1;
  for (int i = 0; i < n; ++i)
    for (int j = i; j < n; ++j)
      for (int k = 0; k < n3; ++k){
        double v = A.M[i][j][k];
        if (j > i) v += A.M[j][i][k];
        if (cabs_(v) > 1e-12){
          if (P.n >= 400) { P.n = -1; return P; }
          P.e[P.n].i = i; P.e[P.n].j = j; P.e[P.n].k = k; P.e[P.n].c = v; P.n++;
        }
      }
  return P;
}

// Off-diagonal pair (l1<l2): check C21[j,i,k] == s*C12[i,j,k], s=+-1.
constexpr PathTab buildPair(int l1, int l2, int l3){
  MTab A = buildM(l1, l2, l3);
  MTab B = buildM(l2, l1, l3);
  const int n1 = 2*l1+1, n2 = 2*l2+1, n3 = 2*l3+1;
  bool okp = true, okm = true;
  for (int i = 0; i < n1; ++i)
    for (int j = 0; j < n2; ++j)
      for (int k = 0; k < n3; ++k){
        double a = A.M[i][j][k], b = B.M[j][i][k];
        if (cabs_(b - a) > 1e-9) okp = false;
        if (cabs_(b + a) > 1e-9) okm = false;
      }
  PathTab P{}; P.n = 0; P.s = okp ? 1 : (okm ? -1 : 0);
  if (P.s == 0) return P;
  for (int i = 0; i < n1; ++i)
    for (int j = 0; j < n2; ++j)
      for (int k = 0; k < n3; ++k){
        double v = A.M[i][j][k];
        if (cabs_(v) > 1e-12){
          if (P.n >= 400) { P.n = -1; return P; }
          P.e[P.n].i = i; P.e[P.n].j = j; P.e[P.n].k = k; P.e[P.n].c = v; P.n++;
        }
      }
  return P;
}

// Raw single path (fallback for s==0 pairs).
constexpr PathTab buildSingleTab(int l1, int l2, int l3){
  MTab A = buildM(l1, l2, l3);
  const int n1 = 2*l1+1, n2 = 2*l2+1, n3 = 2*l3+1;
  PathTab P{}; P.n = 0; P.s = 1;
  for (int i = 0; i < n1; ++i)
    for (int j = 0; j < n2; ++j)
      for (int k = 0; k < n3; ++k){
        double v = A.M[i][j][k];
        if (cabs_(v) > 1e-12){
          if (P.n >= 400) { P.n = -1; return P; }
          P.e[P.n].i = i; P.e[P.n].j = j; P.e[P.n].k = k; P.e[P.n].c = v; P.n++;
        }
      }
  return P;
}

template<int L,int L3>          struct TD_ { static constexpr PathTab t = buildDiag(L, L3); };
template<int L1,int L2,int L3>  struct TP_ { static constexpr PathTab t = buildPair(L1, L2, L3); };
template<int L1,int L2,int L3>  struct TS_ { static constexpr PathTab t = buildSingleTab(L1, L2, L3); };

// weight index in the reference's path enumeration
constexpr int pidx(int lin, int lout, int a, int b, int c){
  int p = 0;
  for (int l1 = 0; l1 <= lin; ++l1)
    for (int l2 = 0; l2 <= lin; ++l2){
      int lo = l1 > l2 ? l1 - l2 : l2 - l1;
      int hi = (l1 + l2 < lout) ? l1 + l2 : lout;
      for (int l3 = lo; l3 <= hi; ++l3){
        if (l1 == a && l2 == b && l3 == c) return p;
        ++p;
      }
    }
  return -1;
}

// ======================= stage-1 group/slot layout =======================
#define G1LIST(X) \
  X(0, 0,0,0) X(1, 1,1,0) X(2, 1,1,1) X(3, 1,1,2) \
  X(4, 2,2,0) X(5, 2,2,1) X(6, 2,2,2) X(7, 2,2,3) X(8, 2,2,4) \
  X(9, 3,3,0) X(10,3,3,1) X(11,3,3,2) X(12,3,3,3) X(13,3,3,4) \
  X(14,0,1,1) X(15,0,2,2) X(16,0,3,3) \
  X(17,1,2,1) X(18,1,2,2) X(19,1,2,3) \
  X(20,1,3,2) X(21,1,3,3) X(22,1,3,4) \
  X(23,2,3,1) X(24,2,3,2) X(25,2,3,3) X(26,2,3,4)

struct Grp { int l1, l2, l3; };
#define G1ITEM(i,a,b,c) {a,b,c},
constexpr Grp G1A[27] = { G1LIST(G1ITEM) };
#undef G1ITEM

struct SlotTab { int base[28]; int s[27]; int total; };
constexpr SlotTab buildSlots(){
  SlotTab T{}; int b = 0;
  for (int i = 0; i < 27; ++i){
    int l1 = G1A[i].l1, l2 = G1A[i].l2, l3 = G1A[i].l3;
    int s = (l1 == l2) ? 1 : buildPair(l1, l2, l3).s;
    T.s[i] = s;
    T.base[i] = b;
    int w = 2*l3 + 1;
    b += (l1 != l2 && s == 0) ? 2*w : w;
  }
  T.base[27] = b; T.total = b;
  return T;
}
constexpr SlotTab ST1 = buildSlots();
constexpr int NS1v = ST1.total;   // 135 when all pairs satisfy s=+-1

// ======================= unrolled helpers =======================

// Kernel A (scalar, per-edge): o[BASE + k] += c * (y_i*y_j)
template<class TT,int L1,int L2,int BASE,int... S>
__device__ __forceinline__ void accS_(const float* __restrict__ y,
                                      float* __restrict__ o,
                                      std::integer_sequence<int, S...>){
  (( o[BASE + TT::t.e[S].k] +=
       (float)TT::t.e[S].c
       * (y[L1*L1 + TT::t.e[S].i] * y[L2*L2 + TT::t.e[S].j]) ), ...);
}
template<class TT,int L1,int L2,int BASE>
__device__ __forceinline__ void accS(const float* __restrict__ y,
                                     float* __restrict__ o){
  accS_<TT,L1,L2,BASE>(y, o, std::make_integer_sequence<int, TT::t.n>{});
}

// z-build (scalar): z[L3^2+k] += w * Se[BASE+k]
template<int L3,int BASE,int... K>
__device__ __forceinline__ void zadds_(float* __restrict__ z,
                                       const float* __restrict__ Se, float w,
                                       std::integer_sequence<int, K...>){
  (( z[L3*L3 + K] = fmaf(w, Se[BASE + K], z[L3*L3 + K]) ), ...);
}
template<int L3,int BASE>
__device__ __forceinline__ void zadds(float* __restrict__ z,
                                      const float* __restrict__ Se, float w){
  zadds_<L3,BASE>(z, Se, w, std::make_integer_sequence<int, 2*L3+1>{});
}

// Stage 2 (scalar, full k, R2-proven expression shape): o[kg] += c*(we*(zi*zj))
template<class TT,int L1,int L2,int L3,int... S>
__device__ __forceinline__ void aps_(const float* __restrict__ y,
                                     float* __restrict__ o, float we,
                                     std::integer_sequence<int, S...>){
  (( o[L3*L3 + TT::t.e[S].k] +=
       (float)TT::t.e[S].c
       * (we * (y[L1*L1 + TT::t.e[S].i] * y[L2*L2 + TT::t.e[S].j])) ), ...);
}
template<class TT,int L1,int L2,int L3>
__device__ __forceinline__ void apply_tabs_(const float* __restrict__ y,
                                            float* __restrict__ o, float we){
  aps_<TT,L1,L2,L3>(y, o, we, std::make_integer_sequence<int, TT::t.n>{});
}

// Stage-2 groups: 19 diag + 23 symmetric pairs (= 65 reference weights).
#define G2LIST(X) \
  X(0,0,0) X(1,1,0) X(1,1,1) X(1,1,2) \
  X(2,2,0) X(2,2,1) X(2,2,2) X(2,2,3) X(2,2,4) \
  X(3,3,0) X(3,3,1) X(3,3,2) X(3,3,3) X(3,3,4) \
  X(4,4,0) X(4,4,1) X(4,4,2) X(4,4,3) X(4,4,4) \
  X(0,1,1) X(0,2,2) X(0,3,3) X(0,4,4) \
  X(1,2,1) X(1,2,2) X(1,2,3) X(1,3,2) X(1,3,3) X(1,3,4) X(1,4,3) X(1,4,4) \
  X(2,3,1) X(2,3,2) X(2,3,3) X(2,3,4) X(2,4,2) X(2,4,3) X(2,4,4) \
  X(3,4,1) X(3,4,2) X(3,4,3) X(3,4,4)

// z-build device function (scalar, full z[25] from LDS S-slice)
static __device__ __forceinline__ void zbuild_s(float* __restrict__ z,
                                                const float* __restrict__ Se,
                                                const float* __restrict__ w1s,
                                                int f){
#define GB(gi,a,b,c) { \
    if constexpr (a == b) { \
      constexpr int pA_ = pidx(3,4,a,a,c); \
      zadds<c, ST1.base[gi]>(z, Se, w1s[pA_*16 + f]); \
    } else if constexpr (ST1.s[gi] != 0) { \
      constexpr int pA_ = pidx(3,4,a,b,c), pB_ = pidx(3,4,b,a,c); \
      const float we = fmaf((float)ST1.s[gi], w1s[pB_*16 + f], w1s[pA_*16 + f]); \
      zadds<c, ST1.base[gi]>(z, Se, we); \
    } else { \
      constexpr int pA_ = pidx(3,4,a,b,c), pB_ = pidx(3,4,b,a,c); \
      zadds<c, ST1.base[gi]>(z, Se, w1s[pA_*16 + f]); \
      zadds<c, ST1.base[gi] + 2*c + 1>(z, Se, w1s[pB_*16 + f]); \
    } }
  G1LIST(GB)
#undef GB
}

// stage-2 device function (scalar, full k, pure-register)
static __device__ __forceinline__ void stage2_s(const float* __restrict__ z,
                                                float* __restrict__ o,
                                                const float* __restrict__ w2s,
                                                int f){
#define G2(a,b,c) { \
    if constexpr (a == b) { \
      constexpr int p_ = pidx(4,4,a,a,c); \
      apply_tabs_<TD_<a,c>, a, b, c>(z, o, w2s[p_*16 + f]); \
    } else if constexpr (TP_<a,b,c>::t.s != 0) { \
      constexpr int pA_ = pidx(4,4,a,b,c), pB_ = pidx(4,4,b,a,c); \
      const float we = fmaf((float)TP_<a,b,c>::t.s, w2s[pB_*16 + f], w2s[pA_*16 + f]); \
      apply_tabs_<TP_<a,b,c>, a, b, c>(z, o, we); \
    } else { \
      constexpr int pA_ = pidx(4,4,a,b,c), pB_ = pidx(4,4,b,a,c); \
      apply_tabs_<TS_<a,b,c>, a, b, c>(z, o, w2s[pA_*16 + f]); \
      apply_tabs_<TS_<b,a,c>, b, a, c>(z, o, w2s[pB_*16 + f]); \
    } }
  G2LIST(G2)
#undef G2
}

// ======================= kernel A: per-edge S basis =======================

__global__ __launch_bounds__(64) void acmd_kernelA(
    const float* __restrict__ disp,
    float* __restrict__ Sg, int E)
{
  __shared__ float tl[64 * NS1v];

  const int lt = threadIdx.x;
  const int e  = blockIdx.x*64 + lt;

  float Sout[NS1v];
#pragma unroll
  for (int k = 0; k < NS1v; ++k) Sout[k] = 0.f;

  if (e < E){
    const float dx = disp[3*e+0], dy = disp[3*e+1], dz = disp[3*e+2];
    const float r  = sqrtf(dx*dx + dy*dy + dz*dz);
    const float x  = r * (1.0f/5.0f);
    const float inv = 1.0f / fmaxf(r, 1e-9f);
    const float ux = dx*inv, uy = dy*inv, uz = dz*inv;
    const float cut = (x < 1.0f) ? expf(1.0f - 1.0f/(1.0f - x*x)) : 0.0f;

    const float sx2 = ux*ux, sy2 = uy*uy, sz2 = uz*uz;
    float s_[16];
    s_[0]  = 0.28209479177387814f;
    s_[1]  = 0.4886025119029199f*uy;
    s_[2]  = 0.4886025119029199f*uz;
    s_[3]  = 0.4886025119029199f*ux;
    s_[4]  = 1.0925484305920792f*ux*uy;
    s_[5]  = 1.0925484305920792f*uy*uz;
    s_[6]  = 0.31539156525252005f*(3.0f*sz2 - 1.0f);
    s_[7]  = 1.0925484305920792f*ux*uz;
    s_[8]  = 0.5462742152960396f*(sx2 - sy2);
    s_[9]  = 0.5900435899266435f*uy*(3.0f*sx2 - sy2);
    s_[10] = 2.890611442640554f*ux*uy*uz;
    s_[11] = 0.4570457994644658f*uy*(5.0f*sz2 - 1.0f);
    s_[12] = 0.3731763325901154f*uz*(5.0f*sz2 - 3.0f);
    s_[13] = 0.4570457994644658f*ux*(5.0f*sz2 - 1.0f);
    s_[14] = 1.445305721320277f*uz*(sx2 - sy2);
    s_[15] = 0.5900435899266435f*ux*(sx2 - 3.0f*sy2);
#pragma unroll
    for (int i = 0; i < 16; ++i) s_[i] *= cut;

#define GA(gi,a,b,c) { \
      if constexpr (a == b) accS<TD_<a,c>, a, b, ST1.base[gi]>(s_, Sout); \
      else if constexpr (ST1.s[gi] != 0) accS<TP_<a,b,c>, a, b, ST1.base[gi]>(s_, Sout); \
      else { accS<TS_<a,b,c>, a, b, ST1.base[gi]>(s_, Sout); \
             accS<TS_<b,a,c>, b, a, ST1.base[gi] + 2*c + 1>(s_, Sout); } }
    G1LIST(GA)
#undef GA
  }

#pragma unroll
  for (int k = 0; k < NS1v; ++k) tl[lt*NS1v + k] = Sout[k];
  __syncthreads();

  const long long base  = (long long)blockIdx.x * 64 * NS1v;
  const long long total = (long long)E * NS1v;
  for (int i = lt; i < 64*NS1v; i += 64){
    long long g = base + i;
    if (g < total) Sg[g] = tl[i];
  }
}

// ======================= kernel C: fused z-build + stage 2, scalar-f ===========
// 256 threads = 16 edges x 16 f. One thread = one radial channel, all 25 k's.
// R12 rationale: scalar-f doubles wave count (32768) -> latency hiding that
// saturated R6-B (89% VALUBusy); pk ops are FLOP-rate-neutral so scalar loses
// nothing on pipe throughput.

__global__ __launch_bounds__(256) void acmd_kernelC(
    const float* __restrict__ disp,
    const float* __restrict__ Sg,
    const float* __restrict__ w1g,
    const float* __restrict__ w2g,
    float* __restrict__ outf, int E)
{
  __shared__ float w1s[40*16];
  __shared__ float w2s[65*16];
  __shared__ float Ss[16 * NS1v];

  for (int i = threadIdx.x; i < 40*16; i += 256) w1s[i] = w1g[i];
  for (int i = threadIdx.x; i < 65*16; i += 256) w2s[i] = w2g[i];
  {
    const long long sbase = (long long)blockIdx.x * 16 * NS1v;
    const long long stot  = (long long)E * NS1v;
    for (int i = threadIdx.x; i < 16*NS1v; i += 256){
      long long g = sbase + i;
      Ss[i] = (g < stot) ? Sg[g] : 0.f;
    }
  }
  __syncthreads();

  const int le = threadIdx.x >> 4;            // local edge 0..15
  const int f  = threadIdx.x & 15;            // radial channel 0..15
  const int e  = blockIdx.x*16 + le;
  if (e >= E) return;                         // no barriers below

  // ---- radial factor ----
  const float dx = disp[3*e+0], dy = disp[3*e+1], dz = disp[3*e+2];
  const float r  = sqrtf(dx*dx + dy*dy + dz*dz);
  const float x  = r * (1.0f/5.0f);
  const float tt = x * (float)(f + 1);
  const float pt = 3.14159265358979f * tt;
  const float rb = (pt > 1e-5f) ? (sinf(pt)/pt) : (1.0f - pt*pt*(1.0f/6.0f));
  const float rb2 = rb*rb;

  const float* Se = &Ss[le * NS1v];

  // ---- z-build (registers) ----
  float z[25];
#pragma unroll
  for (int k = 0; k < 25; ++k) z[k] = 0.f;
  zbuild_s(z, Se, w1s, f);
#pragma unroll
  for (int k = 0; k < 25; ++k) z[k] *= rb2;

  // ---- stage 2 (full k, pure-register) ----
  float o[25];
#pragma unroll
  for (int k = 0; k < 25; ++k) o[k] = 0.f;
  stage2_s(z, o, w2s, f);

  float* dst = outf + (long long)e * 400;
#pragma unroll
  for (int k = 0; k < 25; ++k)
    dst[k*16 + f] = o[k];
}

// ======================= launch =======================

extern "C" void kernel_launch(void* const* d_in, const int* in_sizes, int n_in,
                              void* d_out, int out_size, void* d_ws, size_t ws_size,
                              hipStream_t stream){
  const float* disp = (const float*)d_in[1];   // neighbour_displacements (E,3) f32
  const float* w1   = (const float*)d_in[3];   // tp_weights1 (40,16) f32
  const float* w2   = (const float*)d_in[4];   // tp_weights2 (65,16) f32
  const int E = in_sizes[1] / 3;

  const size_t needS = (size_t)E * NS1v * sizeof(float);
  if (ws_size < needS) return;                 // fail visibly if ws too small
  float* Sg = (float*)d_ws;

  const int blocksA = (E + 63) / 64;
  acmd_kernelA<<<blocksA, 64, 0, stream>>>(disp, Sg, E);

  const int blocksC = (E + 15) / 16;
  acmd_kernelC<<<blocksC, 256, 0, stream>>>(disp, Sg, w1, w2, (float*)d_out, E);
}

// Round 13
// 136.314 us; speedup vs baseline: 1.5223x; 1.0757x over previous
//
#include <hip/hip_runtime.h>
#include <utility>

typedef unsigned int  u32;
typedef unsigned short u16;

// ======================= compile-time real-CG generation =======================
// Mirrors the Python reference exactly: _cg, _u, _real_cg (einsum + R/I pick).

struct CEnt { int i, j, k; double c; };
struct PathTab { int n; int s; CEnt e[400]; };
struct cxd { double re, im; };
struct URow { int n; int col[2]; cxd v[2]; };
struct MTab { double M[9][9][9]; };

constexpr double FT[14] = {1.,1.,2.,6.,24.,120.,720.,5040.,40320.,362880.,
                           3628800.,39916800.,479001600.,6227020800.};

constexpr double cabs_(double x){ return x < 0 ? -x : x; }

constexpr double csqrt_(double x){
  if (x <= 0.) return 0.;
  double g = 1.;
  while (g*g < x) g *= 2.;
  for (int it = 0; it < 50; ++it) g = 0.5*(g + x/g);
  return g;
}

constexpr double cg_(int j1,int m1,int j2,int m2,int j3,int m3){
  if (m1 + m2 != m3) return 0.;
  int dj = j1 - j2; if (dj < 0) dj = -dj;
  if (j3 < dj || j3 > j1 + j2) return 0.;
  double preA = (double)(2*j3+1)*FT[j3+j1-j2]*FT[j3-j1+j2]*FT[j1+j2-j3]/FT[j1+j2+j3+1];
  double preB = FT[j3+m3]*FT[j3-m3]*FT[j1-m1]*FT[j1+m1]*FT[j2-m2]*FT[j2+m2];
  double pre = csqrt_(preA)*csqrt_(preB);
  int kmin = 0;
  if (j2-j3-m1 > kmin) kmin = j2-j3-m1;
  if (j1-j3+m2 > kmin) kmin = j1-j3+m2;
  int kmax = j1+j2-j3;
  if (j1-m1 < kmax) kmax = j1-m1;
  if (j2+m2 < kmax) kmax = j2+m2;
  double s = 0.;
  for (int k = kmin; k <= kmax; ++k){
    double d = FT[k]*FT[j1+j2-j3-k]*FT[j1-m1-k]*FT[j2+m2-k]*FT[j3-j2+m1+k]*FT[j3-j1-m2+k];
    s += ((k & 1) ? -1.0 : 1.0)/d;
  }
  return pre*s;
}

constexpr URow urow_(int l, int r){
  URow R{};
  const double s2 = 0.7071067811865476;
  int m = r - l;
  if (m == 0){ R.n = 1; R.col[0] = l; R.v[0] = {1., 0.}; }
  else if (m > 0){
    R.n = 2;
    R.col[0] = l + m; R.v[0] = { (m & 1) ? -s2 : s2, 0. };
    R.col[1] = l - m; R.v[1] = { s2, 0. };
  } else {
    int mm = -m;
    R.n = 2;
    R.col[0] = l - mm; R.v[0] = { 0., s2 };
    R.col[1] = l + mm; R.v[1] = { 0., (mm & 1) ? s2 : -s2 };
  }
  return R;
}

constexpr cxd cmul_(cxd a, cxd b){ return { a.re*b.re - a.im*b.im, a.re*b.im + a.im*b.re }; }

constexpr MTab buildM(int l1, int l2, int l3){
  const int n1 = 2*l1+1, n2 = 2*l2+1, n3 = 2*l3+1;
  double cgd[9][9][9] = {};
  for (int a = 0; a < n1; ++a)
    for (int b = 0; b < n2; ++b)
      for (int c = 0; c < n3; ++c)
        cgd[a][b][c] = cg_(l1, a-l1, l2, b-l2, l3, c-l3);

  double MR[9][9][9] = {}; double MI[9][9][9] = {};
  double sR = 0., sI = 0.;
  for (int i = 0; i < n1; ++i){
    URow u1 = urow_(l1, i);
    for (int j = 0; j < n2; ++j){
      URow u2 = urow_(l2, j);
      for (int k = 0; k < n3; ++k){
        URow u3 = urow_(l3, k);
        double mre = 0., mim = 0.;
        for (int a = 0; a < u1.n; ++a)
          for (int b = 0; b < u2.n; ++b)
            for (int c = 0; c < u3.n; ++c){
              double cv = cgd[u1.col[a]][u2.col[b]][u3.col[c]];
              if (cv != 0.){
                cxd t = cmul_(u1.v[a], u2.v[b]);
                cxd u3c = { u3.v[c].re, -u3.v[c].im };
                t = cmul_(t, u3c);
                mre += t.re*cv; mim += t.im*cv;
              }
            }
        MR[i][j][k] = mre; MI[i][j][k] = mim;
        sR += cabs_(mre); sI += cabs_(mim);
      }
    }
  }
  const bool useR = (sR >= sI);
  MTab out{};
  for (int i = 0; i < n1; ++i)
    for (int j = 0; j < n2; ++j)
      for (int k = 0; k < n3; ++k)
        out.M[i][j][k] = useR ? MR[i][j][k] : MI[i][j][k];
  return out;
}

// Diagonal family (l1==l2): merge (i,j)/(j,i), i<=j (exact; y1==y2).
constexpr PathTab buildDiag(int l, int l3){
  MTab A = buildM(l, l, l3);
  PathTab P{}; P.n = 0; P.s = 1;
  const int n = 2*l+1, n3 = 2*l3+1;
  for (int i = 0; i < n; ++i)
    for (int j = i; j < n; ++j)
      for (int k = 0; k < n3; ++k){
        double v = A.M[i][j][k];
        if (j > i) v += A.M[j][i][k];
        if (cabs_(v) > 1e-12){
          if (P.n >= 400) { P.n = -1; return P; }
          P.e[P.n].i = i; P.e[P.n].j = j; P.e[P.n].k = k; P.e[P.n].c = v; P.n++;
        }
      }
  return P;
}

// Off-diagonal pair (l1<l2): check C21[j,i,k] == s*C12[i,j,k], s=+-1.
constexpr PathTab buildPair(int l1, int l2, int l3){
  MTab A = buildM(l1, l2, l3);
  MTab B = buildM(l2, l1, l3);
  const int n1 = 2*l1+1, n2 = 2*l2+1, n3 = 2*l3+1;
  bool okp = true, okm = true;
  for (int i = 0; i < n1; ++i)
    for (int j = 0; j < n2; ++j)
      for (int k = 0; k < n3; ++k){
        double a = A.M[i][j][k], b = B.M[j][i][k];
        if (cabs_(b - a) > 1e-9) okp = false;
        if (cabs_(b + a) > 1e-9) okm = false;
      }
  PathTab P{}; P.n = 0; P.s = okp ? 1 : (okm ? -1 : 0);
  if (P.s == 0) return P;
  for (int i = 0; i < n1; ++i)
    for (int j = 0; j < n2; ++j)
      for (int k = 0; k < n3; ++k){
        double v = A.M[i][j][k];
        if (cabs_(v) > 1e-12){
          if (P.n >= 400) { P.n = -1; return P; }
          P.e[P.n].i = i; P.e[P.n].j = j; P.e[P.n].k = k; P.e[P.n].c = v; P.n++;
        }
      }
  return P;
}

template<int L,int L3>          struct TD_ { static constexpr PathTab t = buildDiag(L, L3); };
template<int L1,int L2,int L3>  struct TP_ { static constexpr PathTab t = buildPair(L1, L2, L3); };

// weight index in the reference's path enumeration
constexpr int pidx(int lin, int lout, int a, int b, int c){
  int p = 0;
  for (int l1 = 0; l1 <= lin; ++l1)
    for (int l2 = 0; l2 <= lin; ++l2){
      int lo = l1 > l2 ? l1 - l2 : l2 - l1;
      int hi = (l1 + l2 < lout) ? l1 + l2 : lout;
      for (int l3 = lo; l3 <= hi; ++l3){
        if (l1 == a && l2 == b && l3 == c) return p;
        ++p;
      }
    }
  return -1;
}

// ======================= group lists =======================
// Stage-1: 14 diag + 13 pairs (27 groups).
#define G1LIST(X) \
  X(0, 0,0,0) X(1, 1,1,0) X(2, 1,1,1) X(3, 1,1,2) \
  X(4, 2,2,0) X(5, 2,2,1) X(6, 2,2,2) X(7, 2,2,3) X(8, 2,2,4) \
  X(9, 3,3,0) X(10,3,3,1) X(11,3,3,2) X(12,3,3,3) X(13,3,3,4) \
  X(14,0,1,1) X(15,0,2,2) X(16,0,3,3) \
  X(17,1,2,1) X(18,1,2,2) X(19,1,2,3) \
  X(20,1,3,2) X(21,1,3,3) X(22,1,3,4) \
  X(23,2,3,1) X(24,2,3,2) X(25,2,3,3) X(26,2,3,4)

// Stage-2: 19 diag + 23 pairs (42 groups).
#define G2LIST(X) \
  X(0, 0,0,0) X(1, 1,1,0) X(2, 1,1,1) X(3, 1,1,2) \
  X(4, 2,2,0) X(5, 2,2,1) X(6, 2,2,2) X(7, 2,2,3) X(8, 2,2,4) \
  X(9, 3,3,0) X(10,3,3,1) X(11,3,3,2) X(12,3,3,3) X(13,3,3,4) \
  X(14,4,4,0) X(15,4,4,1) X(16,4,4,2) X(17,4,4,3) X(18,4,4,4) \
  X(19,0,1,1) X(20,0,2,2) X(21,0,3,3) X(22,0,4,4) \
  X(23,1,2,1) X(24,1,2,2) X(25,1,2,3) X(26,1,3,2) X(27,1,3,3) X(28,1,3,4) \
  X(29,1,4,3) X(30,1,4,4) \
  X(31,2,3,1) X(32,2,3,2) X(33,2,3,3) X(34,2,3,4) X(35,2,4,2) X(36,2,4,3) X(37,2,4,4) \
  X(38,3,4,1) X(39,3,4,2) X(40,3,4,3) X(41,3,4,4)

struct Grp { int l1, l2, l3; };
#define G1ITEM(i,a,b,c) {a,b,c},
constexpr Grp G1A[27] = { G1LIST(G1ITEM) };
#undef G1ITEM

struct SlotTab { int base[28]; int s[27]; int total; };
constexpr SlotTab buildSlots(){
  SlotTab T{}; int b = 0;
  for (int i = 0; i < 27; ++i){
    int l1 = G1A[i].l1, l2 = G1A[i].l2, l3 = G1A[i].l3;
    int s = (l1 == l2) ? 1 : buildPair(l1, l2, l3).s;
    T.s[i] = s;
    T.base[i] = b;
    b += 2*l3 + 1;                       // all pairs s=+-1 (asserted below)
  }
  T.base[27] = b; T.total = b;
  return T;
}
constexpr SlotTab ST1 = buildSlots();
constexpr int NS1v = ST1.total;
static_assert(NS1v == 135, "stage-1 pair symmetry broken");
#define G1CK(gi,a,b,c) && (a == b || ST1.s[gi] != 0)
static_assert(true G1LIST(G1CK), "stage-1 pair not +-1");
#undef G1CK
#define G2CK(gi,a,b,c) && (a == b || buildPair(a,b,c).s != 0)
static_assert(true G2LIST(G2CK), "stage-2 pair not +-1");
#undef G2CK

// combined-weight index tables (runtime-indexed, .rodata)
struct WCe { int pA, pB, s; };
#define G1WC(gi,a,b,c) { pidx(3,4,a,b,c), pidx(3,4,b,a,c), (a==b) ? 0 : ST1.s[gi] },
constexpr WCe WC1[27] = { G1LIST(G1WC) };
#undef G1WC
#define G2WC(gi,a,b,c) { pidx(4,4,a,b,c), pidx(4,4,b,a,c), (a==b) ? 0 : buildPair(a,b,c).s },
constexpr WCe WC2[42] = { G2LIST(G2WC) };
#undef G2WC

#define SSTRIDE 136   // padded S row stride (16B-aligned: 136*4 = 544 = 34*16)

// ======================= unrolled helpers =======================

// Kernel A (scalar, per-edge): o[BASE + k] += c * (y_i*y_j)
template<class TT,int L1,int L2,int BASE,int... S>
__device__ __forceinline__ void accS_(const float* __restrict__ y,
                                      float* __restrict__ o,
                                      std::integer_sequence<int, S...>){
  (( o[BASE + TT::t.e[S].k] +=
       (float)TT::t.e[S].c
       * (y[L1*L1 + TT::t.e[S].i] * y[L2*L2 + TT::t.e[S].j]) ), ...);
}
template<class TT,int L1,int L2,int BASE>
__device__ __forceinline__ void accS(const float* __restrict__ y,
                                     float* __restrict__ o){
  accS_<TT,L1,L2,BASE>(y, o, std::make_integer_sequence<int, TT::t.n>{});
}

// z-build (scalar): z[L3^2+k] += w * Se[BASE+k]
template<int L3,int BASE,int... K>
__device__ __forceinline__ void zadds_(float* __restrict__ z,
                                       const float* __restrict__ Se, float w,
                                       std::integer_sequence<int, K...>){
  (( z[L3*L3 + K] = fmaf(w, Se[BASE + K], z[L3*L3 + K]) ), ...);
}
template<int L3,int BASE>
__device__ __forceinline__ void zadds(float* __restrict__ z,
                                      const float* __restrict__ Se, float w){
  zadds_<L3,BASE>(z, Se, w, std::make_integer_sequence<int, 2*L3+1>{});
}

// Stage 2 (scalar, full k, R2-proven expression shape): o[kg] += c*(we*(zi*zj))
template<class TT,int L1,int L2,int L3,int... S>
__device__ __forceinline__ void aps_(const float* __restrict__ y,
                                     float* __restrict__ o, float we,
                                     std::integer_sequence<int, S...>){
  (( o[L3*L3 + TT::t.e[S].k] +=
       (float)TT::t.e[S].c
       * (we * (y[L1*L1 + TT::t.e[S].i] * y[L2*L2 + TT::t.e[S].j])) ), ...);
}
template<class TT,int L1,int L2,int L3>
__device__ __forceinline__ void apply_tabs_(const float* __restrict__ y,
                                            float* __restrict__ o, float we){
  aps_<TT,L1,L2,L3>(y, o, we, std::make_integer_sequence<int, TT::t.n>{});
}

// z-build: all groups are single slot-blocks with pre-combined weights
static __device__ __forceinline__ void zbuild_s(float* __restrict__ z,
                                                const float* __restrict__ Se,
                                                const float* __restrict__ cw1,
                                                int f){
#define GB(gi,a,b,c) zadds<c, ST1.base[gi]>(z, Se, cw1[gi*16 + f]);
  G1LIST(GB)
#undef GB
}

// stage-2: pre-combined weights, diag/pair tables
static __device__ __forceinline__ void stage2_s(const float* __restrict__ z,
                                                float* __restrict__ o,
                                                const float* __restrict__ cw2,
                                                int f){
#define G2(gi,a,b,c) { const float we = cw2[gi*16 + f]; \
    if constexpr (a == b) apply_tabs_<TD_<a,c>, a, b, c>(z, o, we); \
    else                  apply_tabs_<TP_<a,b,c>, a, b, c>(z, o, we); }
  G2LIST(G2)
#undef G2
}

// ======================= kernel A: per-edge S basis (transposed store) =========
// thread = edge; stores S[slot][e] -> lane-consecutive e = coalesced 256B/slot.
// No LDS -> occupancy not LDS-bound (R12 lesson: A was 4 waves/CU).

__global__ __launch_bounds__(256) void acmd_kernelA(
    const float* __restrict__ disp,
    float* __restrict__ Sg, int E)
{
  const int e = blockIdx.x*256 + threadIdx.x;
  if (e >= E) return;

  const float dx = disp[3*e+0], dy = disp[3*e+1], dz = disp[3*e+2];
  const float r  = sqrtf(dx*dx + dy*dy + dz*dz);
  const float x  = r * (1.0f/5.0f);
  const float inv = 1.0f / fmaxf(r, 1e-9f);
  const float ux = dx*inv, uy = dy*inv, uz = dz*inv;
  const float cut = (x < 1.0f) ? expf(1.0f - 1.0f/(1.0f - x*x)) : 0.0f;

  const float sx2 = ux*ux, sy2 = uy*uy, sz2 = uz*uz;
  float s_[16];
  s_[0]  = 0.28209479177387814f;
  s_[1]  = 0.4886025119029199f*uy;
  s_[2]  = 0.4886025119029199f*uz;
  s_[3]  = 0.4886025119029199f*ux;
  s_[4]  = 1.0925484305920792f*ux*uy;
  s_[5]  = 1.0925484305920792f*uy*uz;
  s_[6]  = 0.31539156525252005f*(3.0f*sz2 - 1.0f);
  s_[7]  = 1.0925484305920792f*ux*uz;
  s_[8]  = 0.5462742152960396f*(sx2 - sy2);
  s_[9]  = 0.5900435899266435f*uy*(3.0f*sx2 - sy2);
  s_[10] = 2.890611442640554f*ux*uy*uz;
  s_[11] = 0.4570457994644658f*uy*(5.0f*sz2 - 1.0f);
  s_[12] = 0.3731763325901154f*uz*(5.0f*sz2 - 3.0f);
  s_[13] = 0.4570457994644658f*ux*(5.0f*sz2 - 1.0f);
  s_[14] = 1.445305721320277f*uz*(sx2 - sy2);
  s_[15] = 0.5900435899266435f*ux*(sx2 - 3.0f*sy2);
#pragma unroll
  for (int i = 0; i < 16; ++i) s_[i] *= cut;

  float Sout[NS1v];
#pragma unroll
  for (int k = 0; k < NS1v; ++k) Sout[k] = 0.f;

#define GA(gi,a,b,c) { \
    if constexpr (a == b) accS<TD_<a,c>, a, b, ST1.base[gi]>(s_, Sout); \
    else                  accS<TP_<a,b,c>, a, b, ST1.base[gi]>(s_, Sout); }
  G1LIST(GA)
#undef GA

#pragma unroll
  for (int k = 0; k < NS1v; ++k)
    Sg[(long long)k*E + e] = Sout[k];
}

// ======================= kernel C: fused z-build + stage 2, scalar-f ===========
// 256 threads = 16 edges x 16 f (R12's proven saturated shape), plus:
// - S read from transposed layout into padded [le][136] LDS tile (b128-mergeable)
// - per-f combined weights precomputed once per block (saves 36 fma + 36 reads)

__global__ __launch_bounds__(256) void acmd_kernelC(
    const float* __restrict__ disp,
    const float* __restrict__ Sg,
    const float* __restrict__ w1g,
    const float* __restrict__ w2g,
    float* __restrict__ outf, int E)
{
  __shared__ float cw1s[27*16];
  __shared__ float cw2s[42*16];
  __shared__ __align__(16) float Ss[16 * SSTRIDE];

  for (int i = threadIdx.x; i < 27*16; i += 256){
    const int g = i >> 4, ff = i & 15;
    float w = w1g[WC1[g].pA*16 + ff];
    if (WC1[g].s) w = fmaf((float)WC1[g].s, w1g[WC1[g].pB*16 + ff], w);
    cw1s[i] = w;
  }
  for (int i = threadIdx.x; i < 42*16; i += 256){
    const int g = i >> 4, ff = i & 15;
    float w = w2g[WC2[g].pA*16 + ff];
    if (WC2[g].s) w = fmaf((float)WC2[g].s, w2g[WC2[g].pB*16 + ff], w);
    cw2s[i] = w;
  }
  {
    const long long base = (long long)blockIdx.x * 16;
    for (int i = threadIdx.x; i < 16*NS1v; i += 256){
      const int slot = i >> 4, le = i & 15;
      const long long ee = base + le;
      Ss[le*SSTRIDE + slot] = (ee < E) ? Sg[(long long)slot*E + ee] : 0.f;
    }
  }
  __syncthreads();

  const int le = threadIdx.x >> 4;            // local edge 0..15
  const int f  = threadIdx.x & 15;            // radial channel 0..15
  const int e  = blockIdx.x*16 + le;
  if (e >= E) return;                         // no barriers below

  // ---- radial factor ----
  const float dx = disp[3*e+0], dy = disp[3*e+1], dz = disp[3*e+2];
  const float r  = sqrtf(dx*dx + dy*dy + dz*dz);
  const float x  = r * (1.0f/5.0f);
  const float tt = x * (float)(f + 1);
  const float pt = 3.14159265358979f * tt;
  const float rb = (pt > 1e-5f) ? (sinf(pt)/pt) : (1.0f - pt*pt*(1.0f/6.0f));
  const float rb2 = rb*rb;

  const float* Se = &Ss[le * SSTRIDE];

  // ---- z-build (registers) ----
  float z[25];
#pragma unroll
  for (int k = 0; k < 25; ++k) z[k] = 0.f;
  zbuild_s(z, Se, cw1s, f);
#pragma unroll
  for (int k = 0; k < 25; ++k) z[k] *= rb2;

  // ---- stage 2 (full k, pure-register) ----
  float o[25];
#pragma unroll
  for (int k = 0; k < 25; ++k) o[k] = 0.f;
  stage2_s(z, o, cw2s, f);

  float* dst = outf + (long long)e * 400;
#pragma unroll
  for (int k = 0; k < 25; ++k)
    dst[k*16 + f] = o[k];
}

// ======================= launch =======================

extern "C" void kernel_launch(void* const* d_in, const int* in_sizes, int n_in,
                              void* d_out, int out_size, void* d_ws, size_t ws_size,
                              hipStream_t stream){
  const float* disp = (const float*)d_in[1];   // neighbour_displacements (E,3) f32
  const float* w1   = (const float*)d_in[3];   // tp_weights1 (40,16) f32
  const float* w2   = (const float*)d_in[4];   // tp_weights2 (65,16) f32
  const int E = in_sizes[1] / 3;

  const size_t needS = (size_t)E * NS1v * sizeof(float);
  if (ws_size < needS) return;                 // fail visibly if ws too small
  float* Sg = (float*)d_ws;

  const int blocksA = (E + 255) / 256;
  acmd_kernelA<<<blocksA, 256, 0, stream>>>(disp, Sg, E);

  const int blocksC = (E + 15) / 16;
  acmd_kernelC<<<blocksC, 256, 0, stream>>>(disp, Sg, w1, w2, (float*)d_out, E);
}

// Round 14
// 130.117 us; speedup vs baseline: 1.5948x; 1.0476x over previous
//
#include <hip/hip_runtime.h>
#include <utility>

typedef unsigned int  u32;
typedef unsigned short u16;
typedef float f32x4 __attribute__((ext_vector_type(4)));

// ======================= compile-time real-CG generation =======================
// Mirrors the Python reference exactly: _cg, _u, _real_cg (einsum + R/I pick).

struct CEnt { int i, j, k; double c; };
struct PathTab { int n; int s; CEnt e[400]; };
struct cxd { double re, im; };
struct URow { int n; int col[2]; cxd v[2]; };
struct MTab { double M[9][9][9]; };

constexpr double FT[14] = {1.,1.,2.,6.,24.,120.,720.,5040.,40320.,362880.,
                           3628800.,39916800.,479001600.,6227020800.};

constexpr double cabs_(double x){ return x < 0 ? -x : x; }

constexpr double csqrt_(double x){
  if (x <= 0.) return 0.;
  double g = 1.;
  while (g*g < x) g *= 2.;
  for (int it = 0; it < 50; ++it) g = 0.5*(g + x/g);
  return g;
}

constexpr double cg_(int j1,int m1,int j2,int m2,int j3,int m3){
  if (m1 + m2 != m3) return 0.;
  int dj = j1 - j2; if (dj < 0) dj = -dj;
  if (j3 < dj || j3 > j1 + j2) return 0.;
  double preA = (double)(2*j3+1)*FT[j3+j1-j2]*FT[j3-j1+j2]*FT[j1+j2-j3]/FT[j1+j2+j3+1];
  double preB = FT[j3+m3]*FT[j3-m3]*FT[j1-m1]*FT[j1+m1]*FT[j2-m2]*FT[j2+m2];
  double pre = csqrt_(preA)*csqrt_(preB);
  int kmin = 0;
  if (j2-j3-m1 > kmin) kmin = j2-j3-m1;
  if (j1-j3+m2 > kmin) kmin = j1-j3+m2;
  int kmax = j1+j2-j3;
  if (j1-m1 < kmax) kmax = j1-m1;
  if (j2+m2 < kmax) kmax = j2+m2;
  double s = 0.;
  for (int k = kmin; k <= kmax; ++k){
    double d = FT[k]*FT[j1+j2-j3-k]*FT[j1-m1-k]*FT[j2+m2-k]*FT[j3-j2+m1+k]*FT[j3-j1-m2+k];
    s += ((k & 1) ? -1.0 : 1.0)/d;
  }
  return pre*s;
}

constexpr URow urow_(int l, int r){
  URow R{};
  const double s2 = 0.7071067811865476;
  int m = r - l;
  if (m == 0){ R.n = 1; R.col[0] = l; R.v[0] = {1., 0.}; }
  else if (m > 0){
    R.n = 2;
    R.col[0] = l + m; R.v[0] = { (m & 1) ? -s2 : s2, 0. };
    R.col[1] = l - m; R.v[1] = { s2, 0. };
  } else {
    int mm = -m;
    R.n = 2;
    R.col[0] = l - mm; R.v[0] = { 0., s2 };
    R.col[1] = l + mm; R.v[1] = { 0., (mm & 1) ? s2 : -s2 };
  }
  return R;
}

constexpr cxd cmul_(cxd a, cxd b){ return { a.re*b.re - a.im*b.im, a.re*b.im + a.im*b.re }; }

constexpr MTab buildM(int l1, int l2, int l3){
  const int n1 = 2*l1+1, n2 = 2*l2+1, n3 = 2*l3+1;
  double cgd[9][9][9] = {};
  for (int a = 0; a < n1; ++a)
    for (int b = 0; b < n2; ++b)
      for (int c = 0; c < n3; ++c)
        cgd[a][b][c] = cg_(l1, a-l1, l2, b-l2, l3, c-l3);

  double MR[9][9][9] = {}; double MI[9][9][9] = {};
  double sR = 0., sI = 0.;
  for (int i = 0; i < n1; ++i){
    URow u1 = urow_(l1, i);
    for (int j = 0; j < n2; ++j){
      URow u2 = urow_(l2, j);
      for (int k = 0; k < n3; ++k){
        URow u3 = urow_(l3, k);
        double mre = 0., mim = 0.;
        for (int a = 0; a < u1.n; ++a)
          for (int b = 0; b < u2.n; ++b)
            for (int c = 0; c < u3.n; ++c){
              double cv = cgd[u1.col[a]][u2.col[b]][u3.col[c]];
              if (cv != 0.){
                cxd t = cmul_(u1.v[a], u2.v[b]);
                cxd u3c = { u3.v[c].re, -u3.v[c].im };
                t = cmul_(t, u3c);
                mre += t.re*cv; mim += t.im*cv;
              }
            }
        MR[i][j][k] = mre; MI[i][j][k] = mim;
        sR += cabs_(mre); sI += cabs_(mim);
      }
    }
  }
  const bool useR = (sR >= sI);
  MTab out{};
  for (int i = 0; i < n1; ++i)
    for (int j = 0; j < n2; ++j)
      for (int k = 0; k < n3; ++k)
        out.M[i][j][k] = useR ? MR[i][j][k] : MI[i][j][k];
  return out;
}

// Diagonal family (l1==l2): merge (i,j)/(j,i), i<=j (exact; y1==y2).
constexpr PathTab buildDiag(int l, int l3){
  MTab A = buildM(l, l, l3);
  PathTab P{}; P.n = 0; P.s = 1;
  const int n = 2*l+1, n3 = 2*l3+1;
  for (int i = 0; i < n; ++i)
    for (int j = i; j < n; ++j)
      for (int k = 0; k < n3; ++k){
        double v = A.M[i][j][k];
        if (j > i) v += A.M[j][i][k];
        if (cabs_(v) > 1e-12){
          if (P.n >= 400) { P.n = -1; return P; }
          P.e[P.n].i = i; P.e[P.n].j = j; P.e[P.n].k = k; P.e[P.n].c = v; P.n++;
        }
      }
  return P;
}

// Off-diagonal pair (l1<l2): check C21[j,i,k] == s*C12[i,j,k], s=+-1.
constexpr PathTab buildPair(int l1, int l2, int l3){
  MTab A = buildM(l1, l2, l3);
  MTab B = buildM(l2, l1, l3);
  const int n1 = 2*l1+1, n2 = 2*l2+1, n3 = 2*l3+1;
  bool okp = true, okm = true;
  for (int i = 0; i < n1; ++i)
    for (int j = 0; j < n2; ++j)
      for (int k = 0; k < n3; ++k){
        double a = A.M[i][j][k], b = B.M[j][i][k];
        if (cabs_(b - a) > 1e-9) okp = false;
        if (cabs_(b + a) > 1e-9) okm = false;
      }
  PathTab P{}; P.n = 0; P.s = okp ? 1 : (okm ? -1 : 0);
  if (P.s == 0) return P;
  for (int i = 0; i < n1; ++i)
    for (int j = 0; j < n2; ++j)
      for (int k = 0; k < n3; ++k){
        double v = A.M[i][j][k];
        if (cabs_(v) > 1e-12){
          if (P.n >= 400) { P.n = -1; return P; }
          P.e[P.n].i = i; P.e[P.n].j = j; P.e[P.n].k = k; P.e[P.n].c = v; P.n++;
        }
      }
  return P;
}

template<int L,int L3>          struct TD_ { static constexpr PathTab t = buildDiag(L, L3); };
template<int L1,int L2,int L3>  struct TP_ { static constexpr PathTab t = buildPair(L1, L2, L3); };

// weight index in the reference's path enumeration
constexpr int pidx(int lin, int lout, int a, int b, int c){
  int p = 0;
  for (int l1 = 0; l1 <= lin; ++l1)
    for (int l2 = 0; l2 <= lin; ++l2){
      int lo = l1 > l2 ? l1 - l2 : l2 - l1;
      int hi = (l1 + l2 < lout) ? l1 + l2 : lout;
      for (int l3 = lo; l3 <= hi; ++l3){
        if (l1 == a && l2 == b && l3 == c) return p;
        ++p;
      }
    }
  return -1;
}

// ======================= group lists =======================
// Stage-1: 14 diag + 13 pairs (27 groups).
#define G1LIST(X) \
  X(0, 0,0,0) X(1, 1,1,0) X(2, 1,1,1) X(3, 1,1,2) \
  X(4, 2,2,0) X(5, 2,2,1) X(6, 2,2,2) X(7, 2,2,3) X(8, 2,2,4) \
  X(9, 3,3,0) X(10,3,3,1) X(11,3,3,2) X(12,3,3,3) X(13,3,3,4) \
  X(14,0,1,1) X(15,0,2,2) X(16,0,3,3) \
  X(17,1,2,1) X(18,1,2,2) X(19,1,2,3) \
  X(20,1,3,2) X(21,1,3,3) X(22,1,3,4) \
  X(23,2,3,1) X(24,2,3,2) X(25,2,3,3) X(26,2,3,4)

// Stage-2: 19 diag + 23 pairs (42 groups).
#define G2LIST(X) \
  X(0, 0,0,0) X(1, 1,1,0) X(2, 1,1,1) X(3, 1,1,2) \
  X(4, 2,2,0) X(5, 2,2,1) X(6, 2,2,2) X(7, 2,2,3) X(8, 2,2,4) \
  X(9, 3,3,0) X(10,3,3,1) X(11,3,3,2) X(12,3,3,3) X(13,3,3,4) \
  X(14,4,4,0) X(15,4,4,1) X(16,4,4,2) X(17,4,4,3) X(18,4,4,4) \
  X(19,0,1,1) X(20,0,2,2) X(21,0,3,3) X(22,0,4,4) \
  X(23,1,2,1) X(24,1,2,2) X(25,1,2,3) X(26,1,3,2) X(27,1,3,3) X(28,1,3,4) \
  X(29,1,4,3) X(30,1,4,4) \
  X(31,2,3,1) X(32,2,3,2) X(33,2,3,3) X(34,2,3,4) X(35,2,4,2) X(36,2,4,3) X(37,2,4,4) \
  X(38,3,4,1) X(39,3,4,2) X(40,3,4,3) X(41,3,4,4)

struct Grp { int l1, l2, l3; };
#define G1ITEM(i,a,b,c) {a,b,c},
constexpr Grp G1A[27] = { G1LIST(G1ITEM) };
#undef G1ITEM

struct SlotTab { int base[28]; int s[27]; int total; };
constexpr SlotTab buildSlots(){
  SlotTab T{}; int b = 0;
  for (int i = 0; i < 27; ++i){
    int l1 = G1A[i].l1, l2 = G1A[i].l2, l3 = G1A[i].l3;
    int s = (l1 == l2) ? 1 : buildPair(l1, l2, l3).s;
    T.s[i] = s;
    T.base[i] = b;
    b += 2*l3 + 1;                       // all pairs s=+-1 (asserted below)
  }
  T.base[27] = b; T.total = b;
  return T;
}
constexpr SlotTab ST1 = buildSlots();
constexpr int NS1v = ST1.total;
static_assert(NS1v == 135, "stage-1 pair symmetry broken");
#define G1CK(gi,a,b,c) && (a == b || ST1.s[gi] != 0)
static_assert(true G1LIST(G1CK), "stage-1 pair not +-1");
#undef G1CK
#define G2CK(gi,a,b,c) && (a == b || buildPair(a,b,c).s != 0)
static_assert(true G2LIST(G2CK), "stage-2 pair not +-1");
#undef G2CK

// combined-weight index tables (runtime-indexed, .rodata)
struct WCe { int pA, pB, s; };
#define G1WC(gi,a,b,c) { pidx(3,4,a,b,c), pidx(3,4,b,a,c), (a==b) ? 0 : ST1.s[gi] },
constexpr WCe WC1[27] = { G1LIST(G1WC) };
#undef G1WC
#define G2WC(gi,a,b,c) { pidx(4,4,a,b,c), pidx(4,4,b,a,c), (a==b) ? 0 : buildPair(a,b,c).s },
constexpr WCe WC2[42] = { G2LIST(G2WC) };
#undef G2WC

// ======================= unrolled helpers =======================

// Kernel A (scalar, per-edge): o[BASE + k] += c * (y_i*y_j)
template<class TT,int L1,int L2,int BASE,int... S>
__device__ __forceinline__ void accS_(const float* __restrict__ y,
                                      float* __restrict__ o,
                                      std::integer_sequence<int, S...>){
  (( o[BASE + TT::t.e[S].k] +=
       (float)TT::t.e[S].c
       * (y[L1*L1 + TT::t.e[S].i] * y[L2*L2 + TT::t.e[S].j]) ), ...);
}
template<class TT,int L1,int L2,int BASE>
__device__ __forceinline__ void accS(const float* __restrict__ y,
                                     float* __restrict__ o){
  accS_<TT,L1,L2,BASE>(y, o, std::make_integer_sequence<int, TT::t.n>{});
}

// z-build (scalar, slot-major LDS): z[L3^2+k] += w * Sl[(BASE+k)*16]
// Sl = &Ss[le]; compile-time slot offset -> ds imm; 4 distinct lane addrs
// per instruction (le 0..3 per wave), broadcast within f-groups: conflict-free.
template<int L3,int BASE,int... K>
__device__ __forceinline__ void zadds_(float* __restrict__ z,
                                       const float* __restrict__ Sl, float w,
                                       std::integer_sequence<int, K...>){
  (( z[L3*L3 + K] = fmaf(w, Sl[(BASE + K)*16], z[L3*L3 + K]) ), ...);
}
template<int L3,int BASE>
__device__ __forceinline__ void zadds(float* __restrict__ z,
                                      const float* __restrict__ Sl, float w){
  zadds_<L3,BASE>(z, Sl, w, std::make_integer_sequence<int, 2*L3+1>{});
}

// Stage 2 (scalar, full k, R2-proven expression shape): o[kg] += c*(we*(zi*zj))
template<class TT,int L1,int L2,int L3,int... S>
__device__ __forceinline__ void aps_(const float* __restrict__ y,
                                     float* __restrict__ o, float we,
                                     std::integer_sequence<int, S...>){
  (( o[L3*L3 + TT::t.e[S].k] +=
       (float)TT::t.e[S].c
       * (we * (y[L1*L1 + TT::t.e[S].i] * y[L2*L2 + TT::t.e[S].j])) ), ...);
}
template<class TT,int L1,int L2,int L3>
__device__ __forceinline__ void apply_tabs_(const float* __restrict__ y,
                                            float* __restrict__ o, float we){
  aps_<TT,L1,L2,L3>(y, o, we, std::make_integer_sequence<int, TT::t.n>{});
}

// z-build: all groups single slot-blocks, pre-combined weights
static __device__ __forceinline__ void zbuild_s(float* __restrict__ z,
                                                const float* __restrict__ Sl,
                                                const float* __restrict__ cw1,
                                                int f){
#define GB(gi,a,b,c) zadds<c, ST1.base[gi]>(z, Sl, cw1[gi*16 + f]);
  G1LIST(GB)
#undef GB
}

// stage-2: pre-combined weights, diag/pair tables
static __device__ __forceinline__ void stage2_s(const float* __restrict__ z,
                                                float* __restrict__ o,
                                                const float* __restrict__ cw2,
                                                int f){
#define G2(gi,a,b,c) { const float we = cw2[gi*16 + f]; \
    if constexpr (a == b) apply_tabs_<TD_<a,c>, a, b, c>(z, o, we); \
    else                  apply_tabs_<TP_<a,b,c>, a, b, c>(z, o, we); }
  G2LIST(G2)
#undef G2
}

// ======================= kernel A: per-edge S basis (transposed store) =========
// thread = edge; stores S[slot][e] -> lane-consecutive e = coalesced 1KB/slot.

__global__ __launch_bounds__(256) void acmd_kernelA(
    const float* __restrict__ disp,
    float* __restrict__ Sg, int E)
{
  const int e = blockIdx.x*256 + threadIdx.x;
  if (e >= E) return;

  const float dx = disp[3*e+0], dy = disp[3*e+1], dz = disp[3*e+2];
  const float r  = sqrtf(dx*dx + dy*dy + dz*dz);
  const float x  = r * (1.0f/5.0f);
  const float inv = 1.0f / fmaxf(r, 1e-9f);
  const float ux = dx*inv, uy = dy*inv, uz = dz*inv;
  const float cut = (x < 1.0f) ? expf(1.0f - 1.0f/(1.0f - x*x)) : 0.0f;

  const float sx2 = ux*ux, sy2 = uy*uy, sz2 = uz*uz;
  float s_[16];
  s_[0]  = 0.28209479177387814f;
  s_[1]  = 0.4886025119029199f*uy;
  s_[2]  = 0.4886025119029199f*uz;
  s_[3]  = 0.4886025119029199f*ux;
  s_[4]  = 1.0925484305920792f*ux*uy;
  s_[5]  = 1.0925484305920792f*uy*uz;
  s_[6]  = 0.31539156525252005f*(3.0f*sz2 - 1.0f);
  s_[7]  = 1.0925484305920792f*ux*uz;
  s_[8]  = 0.5462742152960396f*(sx2 - sy2);
  s_[9]  = 0.5900435899266435f*uy*(3.0f*sx2 - sy2);
  s_[10] = 2.890611442640554f*ux*uy*uz;
  s_[11] = 0.4570457994644658f*uy*(5.0f*sz2 - 1.0f);
  s_[12] = 0.3731763325901154f*uz*(5.0f*sz2 - 3.0f);
  s_[13] = 0.4570457994644658f*ux*(5.0f*sz2 - 1.0f);
  s_[14] = 1.445305721320277f*uz*(sx2 - sy2);
  s_[15] = 0.5900435899266435f*ux*(sx2 - 3.0f*sy2);
#pragma unroll
  for (int i = 0; i < 16; ++i) s_[i] *= cut;

  float Sout[NS1v];
#pragma unroll
  for (int k = 0; k < NS1v; ++k) Sout[k] = 0.f;

#define GA(gi,a,b,c) { \
    if constexpr (a == b) accS<TD_<a,c>, a, b, ST1.base[gi]>(s_, Sout); \
    else                  accS<TP_<a,b,c>, a, b, ST1.base[gi]>(s_, Sout); }
  G1LIST(GA)
#undef GA

#pragma unroll
  for (int k = 0; k < NS1v; ++k)
    Sg[(long long)k*E + e] = Sout[k];
}

// ======================= kernel C: fused z-build + stage 2, scalar-f ===========
// 256 threads = 16 edges x 16 f (R12's saturated shape). R13 lesson: staging
// must be conflict-free. Slot-major LDS tile Ss[slot*16+le]: float4 global
// reads + b128 LDS writes (contiguous), broadcast-reads in z-build.

__global__ __launch_bounds__(256) void acmd_kernelC(
    const float* __restrict__ disp,
    const float* __restrict__ Sg,
    const float* __restrict__ w1g,
    const float* __restrict__ w2g,
    float* __restrict__ outf, int E)
{
  __shared__ float cw1s[27*16];
  __shared__ float cw2s[42*16];
  __shared__ __align__(16) float Ss[NS1v*16];   // slot-major: [slot][le]

  for (int i = threadIdx.x; i < 27*16; i += 256){
    const int g = i >> 4, ff = i & 15;
    float w = w1g[WC1[g].pA*16 + ff];
    if (WC1[g].s) w = fmaf((float)WC1[g].s, w1g[WC1[g].pB*16 + ff], w);
    cw1s[i] = w;
  }
  for (int i = threadIdx.x; i < 42*16; i += 256){
    const int g = i >> 4, ff = i & 15;
    float w = w2g[WC2[g].pA*16 + ff];
    if (WC2[g].s) w = fmaf((float)WC2[g].s, w2g[WC2[g].pB*16 + ff], w);
    cw2s[i] = w;
  }
  {
    const long long base = (long long)blockIdx.x * 16;
    if (base + 16 <= E && (E & 3) == 0){
      // fast path: 135*4 float4 elements; lane j -> slot j/4, quad j%4
      for (int j = threadIdx.x; j < NS1v*4; j += 256){
        const int slot = j >> 2, q = j & 3;
        const f32x4 v = *(const f32x4*)&Sg[(long long)slot*E + base + 4*q];
        *(f32x4*)&Ss[slot*16 + 4*q] = v;
      }
    } else {
      for (int i = threadIdx.x; i < NS1v*16; i += 256){
        const int slot = i >> 4, le = i & 15;
        const long long ee = base + le;
        Ss[slot*16 + le] = (ee < E) ? Sg[(long long)slot*E + ee] : 0.f;
      }
    }
  }
  __syncthreads();

  const int le = threadIdx.x >> 4;            // local edge 0..15
  const int f  = threadIdx.x & 15;            // radial channel 0..15
  const int e  = blockIdx.x*16 + le;
  if (e >= E) return;                         // no barriers below

  // ---- radial factor ----
  const float dx = disp[3*e+0], dy = disp[3*e+1], dz = disp[3*e+2];
  const float r  = sqrtf(dx*dx + dy*dy + dz*dz);
  const float x  = r * (1.0f/5.0f);
  const float tt = x * (float)(f + 1);
  const float pt = 3.14159265358979f * tt;
  const float rb = (pt > 1e-5f) ? (sinf(pt)/pt) : (1.0f - pt*pt*(1.0f/6.0f));
  const float rb2 = rb*rb;

  const float* Sl = &Ss[le];   // slot-major: element s at Sl[s*16]

  // ---- z-build (registers) ----
  float z[25];
#pragma unroll
  for (int k = 0; k < 25; ++k) z[k] = 0.f;
  zbuild_s(z, Sl, cw1s, f);
#pragma unroll
  for (int k = 0; k < 25; ++k) z[k] *= rb2;

  // ---- stage 2 (full k, pure-register) ----
  float o[25];
#pragma unroll
  for (int k = 0; k < 25; ++k) o[k] = 0.f;
  stage2_s(z, o, cw2s, f);

  float* dst = outf + (long long)e * 400;
#pragma unroll
  for (int k = 0; k < 25; ++k)
    dst[k*16 + f] = o[k];
}

// ======================= launch =======================

extern "C" void kernel_launch(void* const* d_in, const int* in_sizes, int n_in,
                              void* d_out, int out_size, void* d_ws, size_t ws_size,
                              hipStream_t stream){
  const float* disp = (const float*)d_in[1];   // neighbour_displacements (E,3) f32
  const float* w1   = (const float*)d_in[3];   // tp_weights1 (40,16) f32
  const float* w2   = (const float*)d_in[4];   // tp_weights2 (65,16) f32
  const int E = in_sizes[1] / 3;

  const size_t needS = (size_t)E * NS1v * sizeof(float);
  if (ws_size < needS) return;                 // fail visibly if ws too small
  float* Sg = (float*)d_ws;

  const int blocksA = (E + 255) / 256;
  acmd_kernelA<<<blocksA, 256, 0, stream>>>(disp, Sg, E);

  const int blocksC = (E + 15) / 16;
  acmd_kernelC<<<blocksC, 256, 0, stream>>>(disp, Sg, w1, w2, (float*)d_out, E);
}

// Round 15
// 129.766 us; speedup vs baseline: 1.5991x; 1.0027x over previous
//
#include <hip/hip_runtime.h>
#include <utility>

typedef unsigned int  u32;
typedef unsigned short u16;
typedef float f32x4 __attribute__((ext_vector_type(4)));

// ======================= compile-time real-CG generation =======================
// Mirrors the Python reference exactly: _cg, _u, _real_cg (einsum + R/I pick).

struct CEnt { int i, j, k; double c; };
struct PathTab { int n; int s; CEnt e[400]; };
struct cxd { double re, im; };
struct URow { int n; int col[2]; cxd v[2]; };
struct MTab { double M[9][9][9]; };

constexpr double FT[14] = {1.,1.,2.,6.,24.,120.,720.,5040.,40320.,362880.,
                           3628800.,39916800.,479001600.,6227020800.};

constexpr double cabs_(double x){ return x < 0 ? -x : x; }

constexpr double csqrt_(double x){
  if (x <= 0.) return 0.;
  double g = 1.;
  while (g*g < x) g *= 2.;
  for (int it = 0; it < 50; ++it) g = 0.5*(g + x/g);
  return g;
}

constexpr double cg_(int j1,int m1,int j2,int m2,int j3,int m3){
  if (m1 + m2 != m3) return 0.;
  int dj = j1 - j2; if (dj < 0) dj = -dj;
  if (j3 < dj || j3 > j1 + j2) return 0.;
  double preA = (double)(2*j3+1)*FT[j3+j1-j2]*FT[j3-j1+j2]*FT[j1+j2-j3]/FT[j1+j2+j3+1];
  double preB = FT[j3+m3]*FT[j3-m3]*FT[j1-m1]*FT[j1+m1]*FT[j2-m2]*FT[j2+m2];
  double pre = csqrt_(preA)*csqrt_(preB);
  int kmin = 0;
  if (j2-j3-m1 > kmin) kmin = j2-j3-m1;
  if (j1-j3+m2 > kmin) kmin = j1-j3+m2;
  int kmax = j1+j2-j3;
  if (j1-m1 < kmax) kmax = j1-m1;
  if (j2+m2 < kmax) kmax = j2+m2;
  double s = 0.;
  for (int k = kmin; k <= kmax; ++k){
    double d = FT[k]*FT[j1+j2-j3-k]*FT[j1-m1-k]*FT[j2+m2-k]*FT[j3-j2+m1+k]*FT[j3-j1-m2+k];
    s += ((k & 1) ? -1.0 : 1.0)/d;
  }
  return pre*s;
}

constexpr URow urow_(int l, int r){
  URow R{};
  const double s2 = 0.7071067811865476;
  int m = r - l;
  if (m == 0){ R.n = 1; R.col[0] = l; R.v[0] = {1., 0.}; }
  else if (m > 0){
    R.n = 2;
    R.col[0] = l + m; R.v[0] = { (m & 1) ? -s2 : s2, 0. };
    R.col[1] = l - m; R.v[1] = { s2, 0. };
  } else {
    int mm = -m;
    R.n = 2;
    R.col[0] = l - mm; R.v[0] = { 0., s2 };
    R.col[1] = l + mm; R.v[1] = { 0., (mm & 1) ? s2 : -s2 };
  }
  return R;
}

constexpr cxd cmul_(cxd a, cxd b){ return { a.re*b.re - a.im*b.im, a.re*b.im + a.im*b.re }; }

constexpr MTab buildM(int l1, int l2, int l3){
  const int n1 = 2*l1+1, n2 = 2*l2+1, n3 = 2*l3+1;
  double cgd[9][9][9] = {};
  for (int a = 0; a < n1; ++a)
    for (int b = 0; b < n2; ++b)
      for (int c = 0; c < n3; ++c)
        cgd[a][b][c] = cg_(l1, a-l1, l2, b-l2, l3, c-l3);

  double MR[9][9][9] = {}; double MI[9][9][9] = {};
  double sR = 0., sI = 0.;
  for (int i = 0; i < n1; ++i){
    URow u1 = urow_(l1, i);
    for (int j = 0; j < n2; ++j){
      URow u2 = urow_(l2, j);
      for (int k = 0; k < n3; ++k){
        URow u3 = urow_(l3, k);
        double mre = 0., mim = 0.;
        for (int a = 0; a < u1.n; ++a)
          for (int b = 0; b < u2.n; ++b)
            for (int c = 0; c < u3.n; ++c){
              double cv = cgd[u1.col[a]][u2.col[b]][u3.col[c]];
              if (cv != 0.){
                cxd t = cmul_(u1.v[a], u2.v[b]);
                cxd u3c = { u3.v[c].re, -u3.v[c].im };
                t = cmul_(t, u3c);
                mre += t.re*cv; mim += t.im*cv;
              }
            }
        MR[i][j][k] = mre; MI[i][j][k] = mim;
        sR += cabs_(mre); sI += cabs_(mim);
      }
    }
  }
  const bool useR = (sR >= sI);
  MTab out{};
  for (int i = 0; i < n1; ++i)
    for (int j = 0; j < n2; ++j)
      for (int k = 0; k < n3; ++k)
        out.M[i][j][k] = useR ? MR[i][j][k] : MI[i][j][k];
  return out;
}

// Diagonal family (l1==l2): merge (i,j)/(j,i), i<=j (exact; y1==y2).
constexpr PathTab buildDiag(int l, int l3){
  MTab A = buildM(l, l, l3);
  PathTab P{}; P.n = 0; P.s = 1;
  const int n = 2*l+1, n3 = 2*l3+1;
  for (int i = 0; i < n; ++i)
    for (int j = i; j < n; ++j)
      for (int k = 0; k < n3; ++k){
        double v = A.M[i][j][k];
        if (j > i) v += A.M[j][i][k];
        if (cabs_(v) > 1e-12){
          if (P.n >= 400) { P.n = -1; return P; }
          P.e[P.n].i = i; P.e[P.n].j = j; P.e[P.n].k = k; P.e[P.n].c = v; P.n++;
        }
      }
  return P;
}

// Off-diagonal pair (l1<l2): check C21[j,i,k] == s*C12[i,j,k], s=+-1.
constexpr PathTab buildPair(int l1, int l2, int l3){
  MTab A = buildM(l1, l2, l3);
  MTab B = buildM(l2, l1, l3);
  const int n1 = 2*l1+1, n2 = 2*l2+1, n3 = 2*l3+1;
  bool okp = true, okm = true;
  for (int i = 0; i < n1; ++i)
    for (int j = 0; j < n2; ++j)
      for (int k = 0; k < n3; ++k){
        double a = A.M[i][j][k], b = B.M[j][i][k];
        if (cabs_(b - a) > 1e-9) okp = false;
        if (cabs_(b + a) > 1e-9) okm = false;
      }
  PathTab P{}; P.n = 0; P.s = okp ? 1 : (okm ? -1 : 0);
  if (P.s == 0) return P;
  for (int i = 0; i < n1; ++i)
    for (int j = 0; j < n2; ++j)
      for (int k = 0; k < n3; ++k){
        double v = A.M[i][j][k];
        if (cabs_(v) > 1e-12){
          if (P.n >= 400) { P.n = -1; return P; }
          P.e[P.n].i = i; P.e[P.n].j = j; P.e[P.n].k = k; P.e[P.n].c = v; P.n++;
        }
      }
  return P;
}

template<int L,int L3>          struct TD_ { static constexpr PathTab t = buildDiag(L, L3); };
template<int L1,int L2,int L3>  struct TP_ { static constexpr PathTab t = buildPair(L1, L2, L3); };

// weight index in the reference's path enumeration
constexpr int pidx(int lin, int lout, int a, int b, int c){
  int p = 0;
  for (int l1 = 0; l1 <= lin; ++l1)
    for (int l2 = 0; l2 <= lin; ++l2){
      int lo = l1 > l2 ? l1 - l2 : l2 - l1;
      int hi = (l1 + l2 < lout) ? l1 + l2 : lout;
      for (int l3 = lo; l3 <= hi; ++l3){
        if (l1 == a && l2 == b && l3 == c) return p;
        ++p;
      }
    }
  return -1;
}

// ======================= group lists =======================
// Stage-1: 14 diag + 13 pairs (27 groups).
#define G1LIST(X) \
  X(0, 0,0,0) X(1, 1,1,0) X(2, 1,1,1) X(3, 1,1,2) \
  X(4, 2,2,0) X(5, 2,2,1) X(6, 2,2,2) X(7, 2,2,3) X(8, 2,2,4) \
  X(9, 3,3,0) X(10,3,3,1) X(11,3,3,2) X(12,3,3,3) X(13,3,3,4) \
  X(14,0,1,1) X(15,0,2,2) X(16,0,3,3) \
  X(17,1,2,1) X(18,1,2,2) X(19,1,2,3) \
  X(20,1,3,2) X(21,1,3,3) X(22,1,3,4) \
  X(23,2,3,1) X(24,2,3,2) X(25,2,3,3) X(26,2,3,4)

// Stage-2: 19 diag + 23 pairs (42 groups).
#define G2LIST(X) \
  X(0, 0,0,0) X(1, 1,1,0) X(2, 1,1,1) X(3, 1,1,2) \
  X(4, 2,2,0) X(5, 2,2,1) X(6, 2,2,2) X(7, 2,2,3) X(8, 2,2,4) \
  X(9, 3,3,0) X(10,3,3,1) X(11,3,3,2) X(12,3,3,3) X(13,3,3,4) \
  X(14,4,4,0) X(15,4,4,1) X(16,4,4,2) X(17,4,4,3) X(18,4,4,4) \
  X(19,0,1,1) X(20,0,2,2) X(21,0,3,3) X(22,0,4,4) \
  X(23,1,2,1) X(24,1,2,2) X(25,1,2,3) X(26,1,3,2) X(27,1,3,3) X(28,1,3,4) \
  X(29,1,4,3) X(30,1,4,4) \
  X(31,2,3,1) X(32,2,3,2) X(33,2,3,3) X(34,2,3,4) X(35,2,4,2) X(36,2,4,3) X(37,2,4,4) \
  X(38,3,4,1) X(39,3,4,2) X(40,3,4,3) X(41,3,4,4)

struct Grp { int l1, l2, l3; };
#define G1ITEM(i,a,b,c) {a,b,c},
constexpr Grp G1A[27] = { G1LIST(G1ITEM) };
#undef G1ITEM

struct SlotTab { int base[28]; int s[27]; int total; };
constexpr SlotTab buildSlots(){
  SlotTab T{}; int b = 0;
  for (int i = 0; i < 27; ++i){
    int l1 = G1A[i].l1, l2 = G1A[i].l2, l3 = G1A[i].l3;
    int s = (l1 == l2) ? 1 : buildPair(l1, l2, l3).s;
    T.s[i] = s;
    T.base[i] = b;
    b += 2*l3 + 1;                       // all pairs s=+-1 (asserted below)
  }
  T.base[27] = b; T.total = b;
  return T;
}
constexpr SlotTab ST1 = buildSlots();
constexpr int NS1v = ST1.total;
static_assert(NS1v == 135, "stage-1 pair symmetry broken");
#define G1CK(gi,a,b,c) && (a == b || ST1.s[gi] != 0)
static_assert(true G1LIST(G1CK), "stage-1 pair not +-1");
#undef G1CK
#define G2CK(gi,a,b,c) && (a == b || buildPair(a,b,c).s != 0)
static_assert(true G2LIST(G2CK), "stage-2 pair not +-1");
#undef G2CK

// combined-weight index tables (runtime-indexed, .rodata)
struct WCe { int pA, pB, s; };
#define G1WC(gi,a,b,c) { pidx(3,4,a,b,c), pidx(3,4,b,a,c), (a==b) ? 0 : ST1.s[gi] },
constexpr WCe WC1[27] = { G1LIST(G1WC) };
#undef G1WC
#define G2WC(gi,a,b,c) { pidx(4,4,a,b,c), pidx(4,4,b,a,c), (a==b) ? 0 : buildPair(a,b,c).s },
constexpr WCe WC2[42] = { G2LIST(G2WC) };
#undef G2WC

// ======================= unrolled helpers =======================

// Kernel A (scalar, per-edge): o[BASE + k] += c * (y_i*y_j)
template<class TT,int L1,int L2,int BASE,int... S>
__device__ __forceinline__ void accS_(const float* __restrict__ y,
                                      float* __restrict__ o,
                                      std::integer_sequence<int, S...>){
  (( o[BASE + TT::t.e[S].k] +=
       (float)TT::t.e[S].c
       * (y[L1*L1 + TT::t.e[S].i] * y[L2*L2 + TT::t.e[S].j]) ), ...);
}
template<class TT,int L1,int L2,int BASE>
__device__ __forceinline__ void accS(const float* __restrict__ y,
                                     float* __restrict__ o){
  accS_<TT,L1,L2,BASE>(y, o, std::make_integer_sequence<int, TT::t.n>{});
}

// z-build from register-preloaded S: z[L3^2+k] += w * Sr[BASE+K]
template<int L3,int BASE,int... K>
__device__ __forceinline__ void zadds_(float* __restrict__ z,
                                       const float* __restrict__ Sr, float w,
                                       std::integer_sequence<int, K...>){
  (( z[L3*L3 + K] = fmaf(w, Sr[BASE + K], z[L3*L3 + K]) ), ...);
}
template<int L3,int BASE>
__device__ __forceinline__ void zadds(float* __restrict__ z,
                                      const float* __restrict__ Sr, float w){
  zadds_<L3,BASE>(z, Sr, w, std::make_integer_sequence<int, 2*L3+1>{});
}

// Stage 2 (scalar, full k, R2-proven expression shape): o[kg] += c*(we*(zi*zj))
template<class TT,int L1,int L2,int L3,int... S>
__device__ __forceinline__ void aps_(const float* __restrict__ y,
                                     float* __restrict__ o, float we,
                                     std::integer_sequence<int, S...>){
  (( o[L3*L3 + TT::t.e[S].k] +=
       (float)TT::t.e[S].c
       * (we * (y[L1*L1 + TT::t.e[S].i] * y[L2*L2 + TT::t.e[S].j])) ), ...);
}
template<class TT,int L1,int L2,int L3>
__device__ __forceinline__ void apply_tabs_(const float* __restrict__ y,
                                            float* __restrict__ o, float we){
  aps_<TT,L1,L2,L3>(y, o, we, std::make_integer_sequence<int, TT::t.n>{});
}

// z-build: all groups single slot-blocks, pre-combined weights, register S
static __device__ __forceinline__ void zbuild_s(float* __restrict__ z,
                                                const float* __restrict__ Sr,
                                                const float* __restrict__ cw1,
                                                int f){
#define GB(gi,a,b,c) zadds<c, ST1.base[gi]>(z, Sr, cw1[gi*16 + f]);
  G1LIST(GB)
#undef GB
}

// stage-2: pre-combined weights, diag/pair tables
static __device__ __forceinline__ void stage2_s(const float* __restrict__ z,
                                                float* __restrict__ o,
                                                const float* __restrict__ cw2,
                                                int f){
#define G2(gi,a,b,c) { const float we = cw2[gi*16 + f]; \
    if constexpr (a == b) apply_tabs_<TD_<a,c>, a, b, c>(z, o, we); \
    else                  apply_tabs_<TP_<a,b,c>, a, b, c>(z, o, we); }
  G2LIST(G2)
#undef G2
}

// ======================= kernel A: per-edge S basis (transposed store) =========
// thread = edge; stores S[slot][e] -> lane-consecutive e = coalesced 1KB/slot.

__global__ __launch_bounds__(256) void acmd_kernelA(
    const float* __restrict__ disp,
    float* __restrict__ Sg, int E)
{
  const int e = blockIdx.x*256 + threadIdx.x;
  if (e >= E) return;

  const float dx = disp[3*e+0], dy = disp[3*e+1], dz = disp[3*e+2];
  const float r  = sqrtf(dx*dx + dy*dy + dz*dz);
  const float x  = r * (1.0f/5.0f);
  const float inv = 1.0f / fmaxf(r, 1e-9f);
  const float ux = dx*inv, uy = dy*inv, uz = dz*inv;
  const float cut = (x < 1.0f) ? expf(1.0f - 1.0f/(1.0f - x*x)) : 0.0f;

  const float sx2 = ux*ux, sy2 = uy*uy, sz2 = uz*uz;
  float s_[16];
  s_[0]  = 0.28209479177387814f;
  s_[1]  = 0.4886025119029199f*uy;
  s_[2]  = 0.4886025119029199f*uz;
  s_[3]  = 0.4886025119029199f*ux;
  s_[4]  = 1.0925484305920792f*ux*uy;
  s_[5]  = 1.0925484305920792f*uy*uz;
  s_[6]  = 0.31539156525252005f*(3.0f*sz2 - 1.0f);
  s_[7]  = 1.0925484305920792f*ux*uz;
  s_[8]  = 0.5462742152960396f*(sx2 - sy2);
  s_[9]  = 0.5900435899266435f*uy*(3.0f*sx2 - sy2);
  s_[10] = 2.890611442640554f*ux*uy*uz;
  s_[11] = 0.4570457994644658f*uy*(5.0f*sz2 - 1.0f);
  s_[12] = 0.3731763325901154f*uz*(5.0f*sz2 - 3.0f);
  s_[13] = 0.4570457994644658f*ux*(5.0f*sz2 - 1.0f);
  s_[14] = 1.445305721320277f*uz*(sx2 - sy2);
  s_[15] = 0.5900435899266435f*ux*(sx2 - 3.0f*sy2);
#pragma unroll
  for (int i = 0; i < 16; ++i) s_[i] *= cut;

  float Sout[NS1v];
#pragma unroll
  for (int k = 0; k < NS1v; ++k) Sout[k] = 0.f;

#define GA(gi,a,b,c) { \
    if constexpr (a == b) accS<TD_<a,c>, a, b, ST1.base[gi]>(s_, Sout); \
    else                  accS<TP_<a,b,c>, a, b, ST1.base[gi]>(s_, Sout); }
  G1LIST(GA)
#undef GA

#pragma unroll
  for (int k = 0; k < NS1v; ++k)
    Sg[(long long)k*E + e] = Sout[k];
}

// ======================= kernel C: fused z-build + stage 2, scalar-f ===========
// 256 threads = 16 edges x 16 f. R14 lesson: VGPRs are free up to 256/wave at
// 8 waves/SIMD (VGPR was 48). Bulk-preload all 135 S values into registers
// (back-to-back ds_reads, latency amortized once) -> pure-FMA body, no
// read->FMA dependency stalls in z-build.

__global__ __launch_bounds__(256) void acmd_kernelC(
    const float* __restrict__ disp,
    const float* __restrict__ Sg,
    const float* __restrict__ w1g,
    const float* __restrict__ w2g,
    float* __restrict__ outf, int E)
{
  __shared__ float cw1s[27*16];
  __shared__ float cw2s[42*16];
  __shared__ __align__(16) float Ss[NS1v*16];   // slot-major: [slot][le]

  for (int i = threadIdx.x; i < 27*16; i += 256){
    const int g = i >> 4, ff = i & 15;
    float w = w1g[WC1[g].pA*16 + ff];
    if (WC1[g].s) w = fmaf((float)WC1[g].s, w1g[WC1[g].pB*16 + ff], w);
    cw1s[i] = w;
  }
  for (int i = threadIdx.x; i < 42*16; i += 256){
    const int g = i >> 4, ff = i & 15;
    float w = w2g[WC2[g].pA*16 + ff];
    if (WC2[g].s) w = fmaf((float)WC2[g].s, w2g[WC2[g].pB*16 + ff], w);
    cw2s[i] = w;
  }
  {
    const long long base = (long long)blockIdx.x * 16;
    if (base + 16 <= E && (E & 3) == 0){
      // fast path: 135*4 float4 elements; lane j -> slot j/4, quad j%4
      for (int j = threadIdx.x; j < NS1v*4; j += 256){
        const int slot = j >> 2, q = j & 3;
        const f32x4 v = *(const f32x4*)&Sg[(long long)slot*E + base + 4*q];
        *(f32x4*)&Ss[slot*16 + 4*q] = v;
      }
    } else {
      for (int i = threadIdx.x; i < NS1v*16; i += 256){
        const int slot = i >> 4, le = i & 15;
        const long long ee = base + le;
        Ss[slot*16 + le] = (ee < E) ? Sg[(long long)slot*E + ee] : 0.f;
      }
    }
  }
  __syncthreads();

  const int le = threadIdx.x >> 4;            // local edge 0..15
  const int f  = threadIdx.x & 15;            // radial channel 0..15
  const int e  = blockIdx.x*16 + le;
  if (e >= E) return;                         // no barriers below

  // ---- radial factor ----
  const float dx = disp[3*e+0], dy = disp[3*e+1], dz = disp[3*e+2];
  const float r  = sqrtf(dx*dx + dy*dy + dz*dz);
  const float x  = r * (1.0f/5.0f);
  const float tt = x * (float)(f + 1);
  const float pt = 3.14159265358979f * tt;
  const float rb = (pt > 1e-5f) ? (sinf(pt)/pt) : (1.0f - pt*pt*(1.0f/6.0f));
  const float rb2 = rb*rb;

  // ---- bulk S preload into registers (static indices -> VGPRs) ----
  float Sreg[NS1v];
#pragma unroll
  for (int s = 0; s < NS1v; ++s) Sreg[s] = Ss[s*16 + le];

  // ---- z-build (pure FMA on registers) ----
  float z[25];
#pragma unroll
  for (int k = 0; k < 25; ++k) z[k] = 0.f;
  zbuild_s(z, Sreg, cw1s, f);
#pragma unroll
  for (int k = 0; k < 25; ++k) z[k] *= rb2;

  // ---- stage 2 (full k, pure-register) ----
  float o[25];
#pragma unroll
  for (int k = 0; k < 25; ++k) o[k] = 0.f;
  stage2_s(z, o, cw2s, f);

  float* dst = outf + (long long)e * 400;
#pragma unroll
  for (int k = 0; k < 25; ++k)
    dst[k*16 + f] = o[k];
}

// ======================= launch =======================

extern "C" void kernel_launch(void* const* d_in, const int* in_sizes, int n_in,
                              void* d_out, int out_size, void* d_ws, size_t ws_size,
                              hipStream_t stream){
  const float* disp = (const float*)d_in[1];   // neighbour_displacements (E,3) f32
  const float* w1   = (const float*)d_in[3];   // tp_weights1 (40,16) f32
  const float* w2   = (const float*)d_in[4];   // tp_weights2 (65,16) f32
  const int E = in_sizes[1] / 3;

  const size_t needS = (size_t)E * NS1v * sizeof(float);
  if (ws_size < needS) return;                 // fail visibly if ws too small
  float* Sg = (float*)d_ws;

  const int blocksA = (E + 255) / 256;
  acmd_kernelA<<<blocksA, 256, 0, stream>>>(disp, Sg, E);

  const int blocksC = (E + 15) / 16;
  acmd_kernelC<<<blocksC, 256, 0, stream>>>(disp, Sg, w1, w2, (float*)d_out, E);
}

// Round 16
// 124.517 us; speedup vs baseline: 1.6665x; 1.0421x over previous
//
#include <hip/hip_runtime.h>
#include <utility>

typedef unsigned int  u32;
typedef unsigned short u16;
typedef float f32x4 __attribute__((ext_vector_type(4)));

// ======================= compile-time real-CG generation =======================
// Mirrors the Python reference exactly: _cg, _u, _real_cg (einsum + R/I pick).

struct CEnt { int i, j, k; double c; };
struct PathTab { int n; int s; CEnt e[400]; };
struct cxd { double re, im; };
struct URow { int n; int col[2]; cxd v[2]; };
struct MTab { double M[9][9][9]; };

constexpr double FT[14] = {1.,1.,2.,6.,24.,120.,720.,5040.,40320.,362880.,
                           3628800.,39916800.,479001600.,6227020800.};

constexpr double cabs_(double x){ return x < 0 ? -x : x; }

constexpr double csqrt_(double x){
  if (x <= 0.) return 0.;
  double g = 1.;
  while (g*g < x) g *= 2.;
  for (int it = 0; it < 50; ++it) g = 0.5*(g + x/g);
  return g;
}

constexpr double cg_(int j1,int m1,int j2,int m2,int j3,int m3){
  if (m1 + m2 != m3) return 0.;
  int dj = j1 - j2; if (dj < 0) dj = -dj;
  if (j3 < dj || j3 > j1 + j2) return 0.;
  double preA = (double)(2*j3+1)*FT[j3+j1-j2]*FT[j3-j1+j2]*FT[j1+j2-j3]/FT[j1+j2+j3+1];
  double preB = FT[j3+m3]*FT[j3-m3]*FT[j1-m1]*FT[j1+m1]*FT[j2-m2]*FT[j2+m2];
  double pre = csqrt_(preA)*csqrt_(preB);
  int kmin = 0;
  if (j2-j3-m1 > kmin) kmin = j2-j3-m1;
  if (j1-j3+m2 > kmin) kmin = j1-j3+m2;
  int kmax = j1+j2-j3;
  if (j1-m1 < kmax) kmax = j1-m1;
  if (j2+m2 < kmax) kmax = j2+m2;
  double s = 0.;
  for (int k = kmin; k <= kmax; ++k){
    double d = FT[k]*FT[j1+j2-j3-k]*FT[j1-m1-k]*FT[j2+m2-k]*FT[j3-j2+m1+k]*FT[j3-j1-m2+k];
    s += ((k & 1) ? -1.0 : 1.0)/d;
  }
  return pre*s;
}

constexpr URow urow_(int l, int r){
  URow R{};
  const double s2 = 0.7071067811865476;
  int m = r - l;
  if (m == 0){ R.n = 1; R.col[0] = l; R.v[0] = {1., 0.}; }
  else if (m > 0){
    R.n = 2;
    R.col[0] = l + m; R.v[0] = { (m & 1) ? -s2 : s2, 0. };
    R.col[1] = l - m; R.v[1] = { s2, 0. };
  } else {
    int mm = -m;
    R.n = 2;
    R.col[0] = l - mm; R.v[0] = { 0., s2 };
    R.col[1] = l + mm; R.v[1] = { 0., (mm & 1) ? s2 : -s2 };
  }
  return R;
}

constexpr cxd cmul_(cxd a, cxd b){ return { a.re*b.re - a.im*b.im, a.re*b.im + a.im*b.re }; }

constexpr MTab buildM(int l1, int l2, int l3){
  const int n1 = 2*l1+1, n2 = 2*l2+1, n3 = 2*l3+1;
  double cgd[9][9][9] = {};
  for (int a = 0; a < n1; ++a)
    for (int b = 0; b < n2; ++b)
      for (int c = 0; c < n3; ++c)
        cgd[a][b][c] = cg_(l1, a-l1, l2, b-l2, l3, c-l3);

  double MR[9][9][9] = {}; double MI[9][9][9] = {};
  double sR = 0., sI = 0.;
  for (int i = 0; i < n1; ++i){
    URow u1 = urow_(l1, i);
    for (int j = 0; j < n2; ++j){
      URow u2 = urow_(l2, j);
      for (int k = 0; k < n3; ++k){
        URow u3 = urow_(l3, k);
        double mre = 0., mim = 0.;
        for (int a = 0; a < u1.n; ++a)
          for (int b = 0; b < u2.n; ++b)
            for (int c = 0; c < u3.n; ++c){
              double cv = cgd[u1.col[a]][u2.col[b]][u3.col[c]];
              if (cv != 0.){
                cxd t = cmul_(u1.v[a], u2.v[b]);
                cxd u3c = { u3.v[c].re, -u3.v[c].im };
                t = cmul_(t, u3c);
                mre += t.re*cv; mim += t.im*cv;
              }
            }
        MR[i][j][k] = mre; MI[i][j][k] = mim;
        sR += cabs_(mre); sI += cabs_(mim);
      }
    }
  }
  const bool useR = (sR >= sI);
  MTab out{};
  for (int i = 0; i < n1; ++i)
    for (int j = 0; j < n2; ++j)
      for (int k = 0; k < n3; ++k)
        out.M[i][j][k] = useR ? MR[i][j][k] : MI[i][j][k];
  return out;
}

// Diagonal family (l1==l2): merge (i,j)/(j,i), i<=j (exact; y1==y2).
constexpr PathTab buildDiag(int l, int l3){
  MTab A = buildM(l, l, l3);
  PathTab P{}; P.n = 0; P.s = 1;
  const int n = 2*l+1, n3 = 2*l3+1;
  for (int i = 0; i < n; ++i)
    for (int j = i; j < n; ++j)
      for (int k = 0; k < n3; ++k){
        double v = A.M[i][j][k];
        if (j > i) v += A.M[j][i][k];
        if (cabs_(v) > 1e-12){
          if (P.n >= 400) { P.n = -1; return P; }
          P.e[P.n].i = i; P.e[P.n].j = j; P.e[P.n].k = k; P.e[P.n].c = v; P.n++;
        }
      }
  return P;
}

// Off-diagonal pair (l1<l2): check C21[j,i,k] == s*C12[i,j,k], s=+-1.
constexpr PathTab buildPair(int l1, int l2, int l3){
  MTab A = buildM(l1, l2, l3);
  MTab B = buildM(l2, l1, l3);
  const int n1 = 2*l1+1, n2 = 2*l2+1, n3 = 2*l3+1;
  bool okp = true, okm = true;
  for (int i = 0; i < n1; ++i)
    for (int j = 0; j < n2; ++j)
      for (int k = 0; k < n3; ++k){
        double a = A.M[i][j][k], b = B.M[j][i][k];
        if (cabs_(b - a) > 1e-9) okp = false;
        if (cabs_(b + a) > 1e-9) okm = false;
      }
  PathTab P{}; P.n = 0; P.s = okp ? 1 : (okm ? -1 : 0);
  if (P.s == 0) return P;
  for (int i = 0; i < n1; ++i)
    for (int j = 0; j < n2; ++j)
      for (int k = 0; k < n3; ++k){
        double v = A.M[i][j][k];
        if (cabs_(v) > 1e-12){
          if (P.n >= 400) { P.n = -1; return P; }
          P.e[P.n].i = i; P.e[P.n].j = j; P.e[P.n].k = k; P.e[P.n].c = v; P.n++;
        }
      }
  return P;
}

template<int L,int L3>          struct TD_ { static constexpr PathTab t = buildDiag(L, L3); };
template<int L1,int L2,int L3>  struct TP_ { static constexpr PathTab t = buildPair(L1, L2, L3); };

// weight index in the reference's path enumeration
constexpr int pidx(int lin, int lout, int a, int b, int c){
  int p = 0;
  for (int l1 = 0; l1 <= lin; ++l1)
    for (int l2 = 0; l2 <= lin; ++l2){
      int lo = l1 > l2 ? l1 - l2 : l2 - l1;
      int hi = (l1 + l2 < lout) ? l1 + l2 : lout;
      for (int l3 = lo; l3 <= hi; ++l3){
        if (l1 == a && l2 == b && l3 == c) return p;
        ++p;
      }
    }
  return -1;
}

// ======================= group lists =======================
// Stage-1: 14 diag + 13 pairs (27 groups).
#define G1LIST(X) \
  X(0, 0,0,0) X(1, 1,1,0) X(2, 1,1,1) X(3, 1,1,2) \
  X(4, 2,2,0) X(5, 2,2,1) X(6, 2,2,2) X(7, 2,2,3) X(8, 2,2,4) \
  X(9, 3,3,0) X(10,3,3,1) X(11,3,3,2) X(12,3,3,3) X(13,3,3,4) \
  X(14,0,1,1) X(15,0,2,2) X(16,0,3,3) \
  X(17,1,2,1) X(18,1,2,2) X(19,1,2,3) \
  X(20,1,3,2) X(21,1,3,3) X(22,1,3,4) \
  X(23,2,3,1) X(24,2,3,2) X(25,2,3,3) X(26,2,3,4)

// Stage-2: 19 diag + 23 pairs (42 groups).
#define G2LIST(X) \
  X(0, 0,0,0) X(1, 1,1,0) X(2, 1,1,1) X(3, 1,1,2) \
  X(4, 2,2,0) X(5, 2,2,1) X(6, 2,2,2) X(7, 2,2,3) X(8, 2,2,4) \
  X(9, 3,3,0) X(10,3,3,1) X(11,3,3,2) X(12,3,3,3) X(13,3,3,4) \
  X(14,4,4,0) X(15,4,4,1) X(16,4,4,2) X(17,4,4,3) X(18,4,4,4) \
  X(19,0,1,1) X(20,0,2,2) X(21,0,3,3) X(22,0,4,4) \
  X(23,1,2,1) X(24,1,2,2) X(25,1,2,3) X(26,1,3,2) X(27,1,3,3) X(28,1,3,4) \
  X(29,1,4,3) X(30,1,4,4) \
  X(31,2,3,1) X(32,2,3,2) X(33,2,3,3) X(34,2,3,4) X(35,2,4,2) X(36,2,4,3) X(37,2,4,4) \
  X(38,3,4,1) X(39,3,4,2) X(40,3,4,3) X(41,3,4,4)

struct Grp { int l1, l2, l3; };
#define G1ITEM(i,a,b,c) {a,b,c},
constexpr Grp G1A[27] = { G1LIST(G1ITEM) };
#undef G1ITEM

struct SlotTab { int base[28]; int s[27]; int total; };
constexpr SlotTab buildSlots(){
  SlotTab T{}; int b = 0;
  for (int i = 0; i < 27; ++i){
    int l1 = G1A[i].l1, l2 = G1A[i].l2, l3 = G1A[i].l3;
    int s = (l1 == l2) ? 1 : buildPair(l1, l2, l3).s;
    T.s[i] = s;
    T.base[i] = b;
    b += 2*l3 + 1;                       // all pairs s=+-1 (asserted below)
  }
  T.base[27] = b; T.total = b;
  return T;
}
constexpr SlotTab ST1 = buildSlots();
constexpr int NS1v = ST1.total;
static_assert(NS1v == 135, "stage-1 pair symmetry broken");
#define G1CK(gi,a,b,c) && (a == b || ST1.s[gi] != 0)
static_assert(true G1LIST(G1CK), "stage-1 pair not +-1");
#undef G1CK
#define G2CK(gi,a,b,c) && (a == b || buildPair(a,b,c).s != 0)
static_assert(true G2LIST(G2CK), "stage-2 pair not +-1");
#undef G2CK

// combined-weight index tables (runtime-indexed, .rodata)
struct WCe { int pA, pB, s; };
#define G1WC(gi,a,b,c) { pidx(3,4,a,b,c), pidx(3,4,b,a,c), (a==b) ? 0 : ST1.s[gi] },
constexpr WCe WC1[27] = { G1LIST(G1WC) };
#undef G1WC
#define G2WC(gi,a,b,c) { pidx(4,4,a,b,c), pidx(4,4,b,a,c), (a==b) ? 0 : buildPair(a,b,c).s },
constexpr WCe WC2[42] = { G2LIST(G2WC) };
#undef G2WC

// ======================= unrolled helpers =======================

// Kernel A (scalar, per-edge): o[BASE + k] += c * (y_i*y_j)
template<class TT,int L1,int L2,int BASE,int... S>
__device__ __forceinline__ void accS_(const float* __restrict__ y,
                                      float* __restrict__ o,
                                      std::integer_sequence<int, S...>){
  (( o[BASE + TT::t.e[S].k] +=
       (float)TT::t.e[S].c
       * (y[L1*L1 + TT::t.e[S].i] * y[L2*L2 + TT::t.e[S].j]) ), ...);
}
template<class TT,int L1,int L2,int BASE>
__device__ __forceinline__ void accS(const float* __restrict__ y,
                                     float* __restrict__ o){
  accS_<TT,L1,L2,BASE>(y, o, std::make_integer_sequence<int, TT::t.n>{});
}

// z-build from LDS S-slice: z[L3^2+k] += w * Sl[(BASE+K)*16]
template<int L3,int BASE,int... K>
__device__ __forceinline__ void zadds_(float* __restrict__ z,
                                       const float* __restrict__ Sl, float w,
                                       std::integer_sequence<int, K...>){
  (( z[L3*L3 + K] = fmaf(w, Sl[(BASE + K)*16], z[L3*L3 + K]) ), ...);
}
template<int L3,int BASE>
__device__ __forceinline__ void zadds(float* __restrict__ z,
                                      const float* __restrict__ Sl, float w){
  zadds_<L3,BASE>(z, Sl, w, std::make_integer_sequence<int, 2*L3+1>{});
}

// Stage 2 with operand pre-scaling: ys[i] = we*z[l1-block][i] once per group,
// then o[kg] += c * (ys[i] * z[l2-block][j]).  Exact reassociation of
// c*(we*(zi*zj)); one mul per (i,j) instead of two; o-chain ILP unchanged.
template<class TT,int L1,int L2,int L3,int... S>
__device__ __forceinline__ void aps_(const float* __restrict__ ys,
                                     const float* __restrict__ y,
                                     float* __restrict__ o,
                                     std::integer_sequence<int, S...>){
  (( o[L3*L3 + TT::t.e[S].k] +=
       (float)TT::t.e[S].c
       * (ys[TT::t.e[S].i] * y[L2*L2 + TT::t.e[S].j]) ), ...);
}
template<class TT,int L1,int L2,int L3>
__device__ __forceinline__ void apply_tabs_(const float* __restrict__ y,
                                            float* __restrict__ o, float we){
  float ys[2*L1 + 1];
#pragma unroll
  for (int i = 0; i < 2*L1 + 1; ++i) ys[i] = we * y[L1*L1 + i];
  aps_<TT,L1,L2,L3>(ys, y, o, std::make_integer_sequence<int, TT::t.n>{});
}

// z-build: all groups single slot-blocks, pre-combined weights
static __device__ __forceinline__ void zbuild_s(float* __restrict__ z,
                                                const float* __restrict__ Sl,
                                                const float* __restrict__ cw1,
                                                int f){
#define GB(gi,a,b,c) zadds<c, ST1.base[gi]>(z, Sl, cw1[gi*16 + f]);
  G1LIST(GB)
#undef GB
}

// stage-2: pre-combined weights, diag/pair tables, operand pre-scaling
static __device__ __forceinline__ void stage2_s(const float* __restrict__ z,
                                                float* __restrict__ o,
                                                const float* __restrict__ cw2,
                                                int f){
#define G2(gi,a,b,c) { const float we = cw2[gi*16 + f]; \
    if constexpr (a == b) apply_tabs_<TD_<a,c>, a, b, c>(z, o, we); \
    else                  apply_tabs_<TP_<a,b,c>, a, b, c>(z, o, we); }
  G2LIST(G2)
#undef G2
}

// ======================= kernel A: per-edge S basis (transposed store) =========
// thread = edge; stores S[slot][e] -> lane-consecutive e = coalesced 1KB/slot.

__global__ __launch_bounds__(256) void acmd_kernelA(
    const float* __restrict__ disp,
    float* __restrict__ Sg, int E)
{
  const int e = blockIdx.x*256 + threadIdx.x;
  if (e >= E) return;

  const float dx = disp[3*e+0], dy = disp[3*e+1], dz = disp[3*e+2];
  const float r  = sqrtf(dx*dx + dy*dy + dz*dz);
  const float x  = r * (1.0f/5.0f);
  const float inv = 1.0f / fmaxf(r, 1e-9f);
  const float ux = dx*inv, uy = dy*inv, uz = dz*inv;
  const float cut = (x < 1.0f) ? expf(1.0f - 1.0f/(1.0f - x*x)) : 0.0f;

  const float sx2 = ux*ux, sy2 = uy*uy, sz2 = uz*uz;
  float s_[16];
  s_[0]  = 0.28209479177387814f;
  s_[1]  = 0.4886025119029199f*uy;
  s_[2]  = 0.4886025119029199f*uz;
  s_[3]  = 0.4886025119029199f*ux;
  s_[4]  = 1.0925484305920792f*ux*uy;
  s_[5]  = 1.0925484305920792f*uy*uz;
  s_[6]  = 0.31539156525252005f*(3.0f*sz2 - 1.0f);
  s_[7]  = 1.0925484305920792f*ux*uz;
  s_[8]  = 0.5462742152960396f*(sx2 - sy2);
  s_[9]  = 0.5900435899266435f*uy*(3.0f*sx2 - sy2);
  s_[10] = 2.890611442640554f*ux*uy*uz;
  s_[11] = 0.4570457994644658f*uy*(5.0f*sz2 - 1.0f);
  s_[12] = 0.3731763325901154f*uz*(5.0f*sz2 - 3.0f);
  s_[13] = 0.4570457994644658f*ux*(5.0f*sz2 - 1.0f);
  s_[14] = 1.445305721320277f*uz*(sx2 - sy2);
  s_[15] = 0.5900435899266435f*ux*(sx2 - 3.0f*sy2);
#pragma unroll
  for (int i = 0; i < 16; ++i) s_[i] *= cut;

  float Sout[NS1v];
#pragma unroll
  for (int k = 0; k < NS1v; ++k) Sout[k] = 0.f;

#define GA(gi,a,b,c) { \
    if constexpr (a == b) accS<TD_<a,c>, a, b, ST1.base[gi]>(s_, Sout); \
    else                  accS<TP_<a,b,c>, a, b, ST1.base[gi]>(s_, Sout); }
  G1LIST(GA)
#undef GA

#pragma unroll
  for (int k = 0; k < NS1v; ++k)
    Sg[(long long)k*E + e] = Sout[k];
}

// ======================= kernel C: fused z-build + stage 2, scalar-f ===========
// 256 threads = 16 edges x 16 f. Slot-major conflict-free S tile (R14),
// pre-combined weights (R13), operand-prescaled stage-2 (R16: -~400 muls).

__global__ __launch_bounds__(256) void acmd_kernelC(
    const float* __restrict__ disp,
    const float* __restrict__ Sg,
    const float* __restrict__ w1g,
    const float* __restrict__ w2g,
    float* __restrict__ outf, int E)
{
  __shared__ float cw1s[27*16];
  __shared__ float cw2s[42*16];
  __shared__ __align__(16) float Ss[NS1v*16];   // slot-major: [slot][le]

  for (int i = threadIdx.x; i < 27*16; i += 256){
    const int g = i >> 4, ff = i & 15;
    float w = w1g[WC1[g].pA*16 + ff];
    if (WC1[g].s) w = fmaf((float)WC1[g].s, w1g[WC1[g].pB*16 + ff], w);
    cw1s[i] = w;
  }
  for (int i = threadIdx.x; i < 42*16; i += 256){
    const int g = i >> 4, ff = i & 15;
    float w = w2g[WC2[g].pA*16 + ff];
    if (WC2[g].s) w = fmaf((float)WC2[g].s, w2g[WC2[g].pB*16 + ff], w);
    cw2s[i] = w;
  }
  {
    const long long base = (long long)blockIdx.x * 16;
    if (base + 16 <= E && (E & 3) == 0){
      // fast path: 135*4 float4 elements; lane j -> slot j/4, quad j%4
      for (int j = threadIdx.x; j < NS1v*4; j += 256){
        const int slot = j >> 2, q = j & 3;
        const f32x4 v = *(const f32x4*)&Sg[(long long)slot*E + base + 4*q];
        *(f32x4*)&Ss[slot*16 + 4*q] = v;
      }
    } else {
      for (int i = threadIdx.x; i < NS1v*16; i += 256){
        const int slot = i >> 4, le = i & 15;
        const long long ee = base + le;
        Ss[slot*16 + le] = (ee < E) ? Sg[(long long)slot*E + ee] : 0.f;
      }
    }
  }
  __syncthreads();

  const int le = threadIdx.x >> 4;            // local edge 0..15
  const int f  = threadIdx.x & 15;            // radial channel 0..15
  const int e  = blockIdx.x*16 + le;
  if (e >= E) return;                         // no barriers below

  // ---- radial factor ----
  const float dx = disp[3*e+0], dy = disp[3*e+1], dz = disp[3*e+2];
  const float r  = sqrtf(dx*dx + dy*dy + dz*dz);
  const float x  = r * (1.0f/5.0f);
  const float tt = x * (float)(f + 1);
  const float pt = 3.14159265358979f * tt;
  const float rb = (pt > 1e-5f) ? (sinf(pt)/pt) : (1.0f - pt*pt*(1.0f/6.0f));
  const float rb2 = rb*rb;

  const float* Sl = &Ss[le];   // slot-major: element s at Sl[s*16]

  // ---- z-build (registers) ----
  float z[25];
#pragma unroll
  for (int k = 0; k < 25; ++k) z[k] = 0.f;
  zbuild_s(z, Sl, cw1s, f);
#pragma unroll
  for (int k = 0; k < 25; ++k) z[k] *= rb2;

  // ---- stage 2 (full k, pure-register, prescaled operands) ----
  float o[25];
#pragma unroll
  for (int k = 0; k < 25; ++k) o[k] = 0.f;
  stage2_s(z, o, cw2s, f);

  float* dst = outf + (long long)e * 400;
#pragma unroll
  for (int k = 0; k < 25; ++k)
    dst[k*16 + f] = o[k];
}

// ======================= launch =======================

extern "C" void kernel_launch(void* const* d_in, const int* in_sizes, int n_in,
                              void* d_out, int out_size, void* d_ws, size_t ws_size,
                              hipStream_t stream){
  const float* disp = (const float*)d_in[1];   // neighbour_displacements (E,3) f32
  const float* w1   = (const float*)d_in[3];   // tp_weights1 (40,16) f32
  const float* w2   = (const float*)d_in[4];   // tp_weights2 (65,16) f32
  const int E = in_sizes[1] / 3;

  const size_t needS = (size_t)E * NS1v * sizeof(float);
  if (ws_size < needS) return;                 // fail visibly if ws too small
  float* Sg = (float*)d_ws;

  const int blocksA = (E + 255) / 256;
  acmd_kernelA<<<blocksA, 256, 0, stream>>>(disp, Sg, E);

  const int blocksC = (E + 15) / 16;
  acmd_kernelC<<<blocksC, 256, 0, stream>>>(disp, Sg, w1, w2, (float*)d_out, E);
}